// Round 2
// baseline (489.570 us; speedup 1.0000x reference)
//
#include <hip/hip_runtime.h>

// LinearAttention on MI355X — round 2: f32 I/O (reference dtype), bf16 internals.
// Pipeline: rms1 -> GEMM qkv -> q-softmax(d)/k-softmax(n) -> ctx = k@v^T
//           -> attn = ctx^T@q -> GEMM w_out (+bias) -> rms2.
// ws layout: [xn bf16 33.5MB][qkv bf16 100.7MB][ctx/inv alias 0.5MB][w_bf 2MB]

typedef unsigned short u16;
typedef __attribute__((ext_vector_type(8))) short short8;
typedef __attribute__((ext_vector_type(4))) short short4_t;
typedef __attribute__((ext_vector_type(4))) float f32x4;

static constexpr size_t XN_B  = (size_t)512  * 4096;   // per-batch elems, [512][4096]
static constexpr size_t QKV_B = (size_t)1536 * 4096;   // per-batch elems, [1536][4096]
static constexpr float SQRT512 = 22.62741699796952f;

__device__ __forceinline__ float b2f(u16 u){
  union { unsigned u; float f; } x; x.u = ((unsigned)u) << 16; return x.f;
}
__device__ __forceinline__ u16 f2b(float f){
  union { float f; unsigned u; } x; x.f = f;
  unsigned r = x.u + 0x7FFFu + ((x.u >> 16) & 1u);   // RNE
  return (u16)(r >> 16);
}

// ---- f32 -> bf16 bulk convert (weights), 4 elems/thread
__global__ __launch_bounds__(256)
void kcvt(const float* __restrict__ src, u16* __restrict__ dst){
  size_t i = ((size_t)blockIdx.x * 256 + threadIdx.x) * 4;
  f32x4 v = *(const f32x4*)(src + i);
  short4_t o;
  #pragma unroll
  for (int j = 0; j < 4; j++) o[j] = (short)f2b(v[j]);
  *(short4_t*)(dst + i) = o;
}

// ---- per-pixel sum of squares over 512 channels -> inv = rsqrt(ss + eps)
// grid 512 blocks x 256 thr; block handles 64 pixels x 4 channel-chunks
template<int SRC_F32>
__global__ __launch_bounds__(256)
void ksumsq(const void* __restrict__ srcv, size_t bstride, float* __restrict__ inv){
  int tid = threadIdx.x;
  int px = tid & 63, chunk = tid >> 6;
  int pg = blockIdx.x * 64 + px;            // global pixel 0..32767
  int b = pg >> 12, p = pg & 4095;
  float s = 0.f;
  if constexpr (SRC_F32){
    const float* sp = (const float*)srcv + (size_t)b * bstride + p;
    #pragma unroll 4
    for (int c = chunk * 128; c < chunk * 128 + 128; ++c){
      float v = sp[(size_t)c * 4096]; s += v * v;
    }
  } else {
    const u16* sp = (const u16*)srcv + (size_t)b * bstride + p;
    #pragma unroll 4
    for (int c = chunk * 128; c < chunk * 128 + 128; ++c){
      float v = b2f(sp[(size_t)c * 4096]); s += v * v;
    }
  }
  __shared__ float red[256];
  red[tid] = s;
  __syncthreads();
  if (chunk == 0){
    float t = red[px] + red[px + 64] + red[px + 128] + red[px + 192];
    inv[pg] = rsqrtf(t + 1e-12f);
  }
}

// ---- dst[b,c,p] = src[b,c,p] * inv[b,p] * g[c] * sqrt(512), 4 elems/thread
template<int SRC_F32, int DST_F32>
__global__ __launch_bounds__(256)
void knorm(const void* __restrict__ srcv, size_t sbs, void* __restrict__ dstv, size_t dbs,
           const float* __restrict__ g, const float* __restrict__ inv){
  size_t base = ((size_t)blockIdx.x * 256 + threadIdx.x) * 4;   // flat elem idx
  int p = (int)(base & 4095);
  int c = (int)((base >> 12) & 511);
  int b = (int)(base >> 21);
  float gf = g[c] * SQRT512;
  const float* ip = inv + b * 4096 + p;
  float v[4];
  if constexpr (SRC_F32){
    const float* sp = (const float*)srcv + (size_t)b * sbs + (size_t)c * 4096 + p;
    f32x4 t = *(const f32x4*)sp;
    #pragma unroll
    for (int j = 0; j < 4; j++) v[j] = t[j];
  } else {
    const u16* sp = (const u16*)srcv + (size_t)b * sbs + (size_t)c * 4096 + p;
    short4_t t = *(const short4_t*)sp;
    #pragma unroll
    for (int j = 0; j < 4; j++) v[j] = b2f((u16)t[j]);
  }
  #pragma unroll
  for (int j = 0; j < 4; j++) v[j] *= ip[j] * gf;
  if constexpr (DST_F32){
    float* dp = (float*)dstv + (size_t)b * dbs + (size_t)c * 4096 + p;
    f32x4 o;
    #pragma unroll
    for (int j = 0; j < 4; j++) o[j] = v[j];
    *(f32x4*)dp = o;
  } else {
    u16* dp = (u16*)dstv + (size_t)b * dbs + (size_t)c * 4096 + p;
    short4_t o;
    #pragma unroll
    for (int j = 0; j < 4; j++) o[j] = (short)f2b(v[j]);
    *(short4_t*)dp = o;
  }
}

// ---- q softmax over d (64 channels within head), then / SCALE(=8); in place (bf16)
__global__ __launch_bounds__(256)
void qsoftmax(u16* __restrict__ qkv){
  int idx = blockIdx.x * 256 + threadIdx.x;   // 0..262143 = (b,h,n)
  int n = idx & 4095;
  int bh = idx >> 12; int b = bh >> 3, h = bh & 7;
  u16* qp = qkv + (size_t)b * QKV_B + (size_t)(h * 64) * 4096 + n;
  float v[64], mx = -1e30f;
  #pragma unroll
  for (int d = 0; d < 64; d++){ v[d] = b2f(qp[(size_t)d * 4096]); mx = fmaxf(mx, v[d]); }
  float s = 0.f;
  #pragma unroll
  for (int d = 0; d < 64; d++){ v[d] = __expf(v[d] - mx); s += v[d]; }
  float r = 1.f / (s * 8.0f);                 // SCALE = sqrt(64) = 8
  #pragma unroll
  for (int d = 0; d < 64; d++) qp[(size_t)d * 4096] = f2b(v[d] * r);
}

// ---- k softmax over n (4096), one block per (b, channel) row; in place (bf16)
__global__ __launch_bounds__(256)
void ksoftmax(u16* __restrict__ qkv){
  int row = blockIdx.x;                       // 0..4095
  int b = row >> 9, c = row & 511;
  u16* kp = qkv + (size_t)b * QKV_B + (size_t)(512 + c) * 4096;
  int tid = threadIdx.x;
  float v[16], mx = -1e30f;
  #pragma unroll
  for (int j = 0; j < 16; j++){ v[j] = b2f(kp[tid + j * 256]); mx = fmaxf(mx, v[j]); }
  #pragma unroll
  for (int o = 32; o >= 1; o >>= 1) mx = fmaxf(mx, __shfl_xor(mx, o));
  __shared__ float redm[4], reds[4];
  if ((tid & 63) == 0) redm[tid >> 6] = mx;
  __syncthreads();
  mx = fmaxf(fmaxf(redm[0], redm[1]), fmaxf(redm[2], redm[3]));
  float s = 0.f;
  #pragma unroll
  for (int j = 0; j < 16; j++){ v[j] = __expf(v[j] - mx); s += v[j]; }
  #pragma unroll
  for (int o = 32; o >= 1; o >>= 1) s += __shfl_xor(s, o);
  if ((tid & 63) == 0) reds[tid >> 6] = s;
  __syncthreads();
  s = reds[0] + reds[1] + reds[2] + reds[3];
  float r = 1.f / s;
  #pragma unroll
  for (int j = 0; j < 16; j++) kp[tid + j * 256] = f2b(v[j] * r);
}

// ---- generic 64x64-tile bf16 MFMA GEMM, 4 waves, 2x2 16x16x32 frags/wave.
// MODE 0: qkv  = w_qkv[1536,512] @ xn[512,4096]      (per batch z=0..7)
// MODE 1: out2 = w_out[512,512] @ attn[512,4096] + b (per batch; C -> q-segment)
// MODE 2: attn = ctxT[64,64] @ q[64,4096]            (z = b*8+h; C -> xn buffer)
// MODE 3: ctx  = k[64,4096] @ v^T[4096,64]           (z = b*8+h; store C^T)
template<int MODE>
__global__ __launch_bounds__(256)
void gemm_k(const u16* __restrict__ W, const float* __restrict__ bias,
            u16* __restrict__ xnbuf, u16* __restrict__ qkvbuf, u16* __restrict__ ctxbuf)
{
  constexpr int K   = (MODE <= 1) ? 512 : (MODE == 2 ? 64 : 4096);
  constexpr int LDA = (MODE <= 1) ? 512 : (MODE == 2 ? 64 : 4096);
  const int z = blockIdx.z;
  const u16* A; const u16* Bp; u16* C;
  if constexpr (MODE == 0){
    A = W; Bp = xnbuf + (size_t)z * XN_B; C = qkvbuf + (size_t)z * QKV_B;
  } else if constexpr (MODE == 1){
    A = W; Bp = xnbuf + (size_t)z * XN_B; C = qkvbuf + (size_t)z * QKV_B;  // q-seg reuse
  } else if constexpr (MODE == 2){
    int b = z >> 3, h = z & 7;
    A  = ctxbuf + (size_t)z * 4096;                                  // ctxT [e][d]
    Bp = qkvbuf + (size_t)b * QKV_B + (size_t)(h * 64) * 4096;       // q [d][n]
    C  = xnbuf  + (size_t)b * XN_B  + (size_t)(h * 64) * 4096;       // attn [e][n]
  } else {
    int b = z >> 3, h = z & 7;
    A  = qkvbuf + (size_t)b * QKV_B + (size_t)(512  + h * 64) * 4096; // k [d][n]
    Bp = qkvbuf + (size_t)b * QKV_B + (size_t)(1024 + h * 64) * 4096; // v [e][n]
    C  = ctxbuf + (size_t)z * 4096;                                   // store ctxT
  }

  __shared__ u16 As[64 * 40];   // [row m][k], stride 40 (pad 8) -> 16B-aligned rows
  __shared__ u16 Bs[64 * 40];   // [col n][k]
  const int tid = threadIdx.x;
  const int m0 = blockIdx.y * 64;
  const int n0 = blockIdx.x * 64;
  const int wid = tid >> 6, lane = tid & 63;
  const int wr = (wid >> 1) * 32, wc = (wid & 1) * 32;
  const int lr = lane & 15, kb = lane >> 4;
  const int ar = tid >> 2, ac = (tid & 3) << 3;      // A stage: 8 elems/thread
  const int bkr = tid >> 3, bnc = (tid & 7) << 3;    // B stage (transpose path)

  f32x4 acc[2][2] = {};

  for (int k0 = 0; k0 < K; k0 += 32){
    // stage A tile [64][32] direct (k contiguous in global)
    short8 av = *(const short8*)(A + (size_t)(m0 + ar) * LDA + (k0 + ac));
    *(short8*)(As + ar * 40 + ac) = av;
    if constexpr (MODE == 3){
      // v is [e][n] row-major: Bs[col=e][k=n] is a direct copy
      short8 bv = *(const short8*)(Bp + (size_t)ar * 4096 + (k0 + ac));
      *(short8*)(Bs + ar * 40 + ac) = bv;
    } else {
      // B is [k][n] row-major: coalesced global read, transposed LDS write
      short8 bv = *(const short8*)(Bp + (size_t)(k0 + bkr) * 4096 + (n0 + bnc));
      #pragma unroll
      for (int j = 0; j < 8; j++) Bs[(bnc + j) * 40 + bkr] = (u16)bv[j];
    }
    __syncthreads();
    short8 a0 = *(const short8*)(As + (wr +      lr) * 40 + kb * 8);
    short8 a1 = *(const short8*)(As + (wr + 16 + lr) * 40 + kb * 8);
    short8 b0 = *(const short8*)(Bs + (wc +      lr) * 40 + kb * 8);
    short8 b1 = *(const short8*)(Bs + (wc + 16 + lr) * 40 + kb * 8);
    acc[0][0] = __builtin_amdgcn_mfma_f32_16x16x32_bf16(a0, b0, acc[0][0], 0, 0, 0);
    acc[0][1] = __builtin_amdgcn_mfma_f32_16x16x32_bf16(a0, b1, acc[0][1], 0, 0, 0);
    acc[1][0] = __builtin_amdgcn_mfma_f32_16x16x32_bf16(a1, b0, acc[1][0], 0, 0, 0);
    acc[1][1] = __builtin_amdgcn_mfma_f32_16x16x32_bf16(a1, b1, acc[1][1], 0, 0, 0);
    __syncthreads();
  }

  // epilogue: C/D layout col = lane&15, row = (lane>>4)*4 + j  [verified m89]
  #pragma unroll
  for (int mi = 0; mi < 2; mi++)
  #pragma unroll
  for (int ni = 0; ni < 2; ni++)
  #pragma unroll
  for (int j = 0; j < 4; j++){
    int row = m0 + wr + mi * 16 + kb * 4 + j;
    int col = n0 + wc + ni * 16 + lr;
    float val = acc[mi][ni][j];
    if constexpr (MODE == 1) val += bias[row];
    if constexpr (MODE == 3) C[(size_t)col * 64 + row] = f2b(val);   // store ctx^T
    else                     C[(size_t)row * 4096 + col] = f2b(val);
  }
}

extern "C" void kernel_launch(void* const* d_in, const int* in_sizes, int n_in,
                              void* d_out, int out_size, void* d_ws, size_t ws_size,
                              hipStream_t stream)
{
  (void)in_sizes; (void)n_in; (void)out_size; (void)ws_size;
  const float* x    = (const float*)d_in[0];
  const float* g1   = (const float*)d_in[1];
  const float* wqkv = (const float*)d_in[2];
  const float* wout = (const float*)d_in[3];
  const float* bout = (const float*)d_in[4];
  const float* g2   = (const float*)d_in[5];
  float* out = (float*)d_out;
  char* ws = (char*)d_ws;

  u16* xnbuf  = (u16*)(ws);                         // 33,554,432 B (xn, later attn_out)
  u16* qkvbuf = (u16*)(ws + (size_t)33554432);      // 100,663,296 B (qkv; q-seg reused for out2)
  char* tail  = ws + (size_t)134217728;
  float* invbuf = (float*)tail;                     // 131,072 B  } time-disjoint alias
  u16*   ctxbuf = (u16*)tail;                       // 524,288 B  }
  u16* wqkv_bf = (u16*)(ws + (size_t)134742016);    // 1,572,864 B
  u16* wout_bf = (u16*)(ws + (size_t)136314880);    //   524,288 B  (total ws 136.8 MB)

  // 0) weights f32 -> bf16
  kcvt<<<768, 256, 0, stream>>>(wqkv, wqkv_bf);     // 1536*512 = 786432
  kcvt<<<256, 256, 0, stream>>>(wout, wout_bf);     // 512*512  = 262144
  // 1) rms_norm(x, g1) -> xn (bf16)
  ksumsq<1><<<512, 256, 0, stream>>>(x, XN_B, invbuf);
  knorm<1, 0><<<16384, 256, 0, stream>>>(x, XN_B, xnbuf, XN_B, g1, invbuf);
  // 2) qkv = w_qkv @ xn
  gemm_k<0><<<dim3(64, 24, 8), 256, 0, stream>>>(wqkv_bf, nullptr, xnbuf, qkvbuf, ctxbuf);
  // 3) softmaxes in place
  qsoftmax<<<1024, 256, 0, stream>>>(qkvbuf);
  ksoftmax<<<4096, 256, 0, stream>>>(qkvbuf);
  // 4) ctx^T per (b,h)
  gemm_k<3><<<dim3(1, 1, 64), 256, 0, stream>>>(nullptr, nullptr, xnbuf, qkvbuf, ctxbuf);
  // 5) attn = ctx^T @ q  (overwrites xn buffer)
  gemm_k<2><<<dim3(64, 1, 64), 256, 0, stream>>>(nullptr, nullptr, xnbuf, qkvbuf, ctxbuf);
  // 6) out2 = w_out @ attn + b_out  (into q-segment of qkv buffer)
  gemm_k<1><<<dim3(64, 8, 8), 256, 0, stream>>>(wout_bf, bout, xnbuf, qkvbuf, ctxbuf);
  // 7) rms_norm(out2, g2) -> d_out (f32)
  ksumsq<0><<<512, 256, 0, stream>>>(qkvbuf, QKV_B, invbuf);
  knorm<0, 1><<<16384, 256, 0, stream>>>(qkvbuf, QKV_B, out, XN_B, g2, invbuf);
}

// Round 3
// 282.055 us; speedup vs baseline: 1.7357x; 1.7357x over previous
//
#include <hip/hip_runtime.h>

// LinearAttention on MI355X — round 3: all-TN GEMMs + m97-class 128^2 kernel.
// Layouts: xnT[n][c], qT[n][512], kv[b][1024][n], ctxT[bh][e][d], attnT[n][512],
//          out2T[n][512]. rms1/rms2 do the NCHW<->N,C transposes via LDS tiles.
// ws: S1=0(33.5M: xnT->P->attnT) S2=33.5M(qT->out2T) S3=67.1M(kv)
//     E=134217728(w_bf; wq region later reused for ctxT) F=136314880(inv) ~136.4MB

typedef unsigned short u16;
typedef __attribute__((ext_vector_type(8))) short short8;
typedef __attribute__((ext_vector_type(4))) short short4_t;
typedef __attribute__((ext_vector_type(4))) float f32x4;

static constexpr size_t XN_B = (size_t)512 * 4096;    // per-batch elems of [512][4096]
static constexpr size_t KV_B = (size_t)1024 * 4096;   // per-batch elems of kv
static constexpr float SQRT512 = 22.62741699796952f;

typedef const __attribute__((address_space(1))) unsigned int gu32;
typedef __attribute__((address_space(3))) unsigned int lu32;

__device__ __forceinline__ float b2f(u16 u){
  union { unsigned u; float f; } x; x.u = ((unsigned)u) << 16; return x.f;
}
__device__ __forceinline__ u16 f2b(float f){
  union { float f; unsigned u; } x; x.f = f;
  unsigned r = x.u + 0x7FFFu + ((x.u >> 16) & 1u);   // RNE
  return (u16)(r >> 16);
}
__device__ __forceinline__ void gl16(const u16* g, u16* l){
  __builtin_amdgcn_global_load_lds((gu32*)g, (lu32*)l, 16, 0, 0);
}

// ---- f32 -> bf16 bulk convert (weights)
__global__ __launch_bounds__(256)
void kcvt(const float* __restrict__ src, u16* __restrict__ dst){
  size_t i = ((size_t)blockIdx.x * 256 + threadIdx.x) * 4;
  f32x4 v = *(const f32x4*)(src + i);
  short4_t o;
  #pragma unroll
  for (int j = 0; j < 4; j++) o[j] = (short)f2b(v[j]);
  *(short4_t*)(dst + i) = o;
}

// ---- per-pixel sumsq over 512 channels of x [b][c][p] f32 -> inv
__global__ __launch_bounds__(256)
void ksumsq(const float* __restrict__ src, float* __restrict__ inv){
  int tid = threadIdx.x;
  int px = tid & 63, chunk = tid >> 6;
  int pg = blockIdx.x * 64 + px;
  int b = pg >> 12, p = pg & 4095;
  const float* sp = src + (size_t)b * XN_B + p;
  float s = 0.f;
  #pragma unroll 4
  for (int c = chunk * 128; c < chunk * 128 + 128; ++c){
    float v = sp[(size_t)c * 4096]; s += v * v;
  }
  __shared__ float red[256];
  red[tid] = s;
  __syncthreads();
  if (chunk == 0){
    float t = red[px] + red[px + 64] + red[px + 128] + red[px + 192];
    inv[pg] = rsqrtf(t + 1e-12f);
  }
}

// ---- rms1 + transpose: x [c][p] f32 -> xnT [p][c] bf16 (64x64 tiles)
__global__ __launch_bounds__(256)
void knormT(const float* __restrict__ x, const float* __restrict__ g,
            const float* __restrict__ inv, u16* __restrict__ xnT){
  __shared__ u16 lt[64][72];
  int t = threadIdx.x;
  int pg0 = blockIdx.x * 64, c0 = blockIdx.y * 64;
  int b = pg0 >> 12, p0 = pg0 & 4095;
  int pl = t & 63, w = t >> 6;
  float iv = inv[pg0 + pl];
  #pragma unroll
  for (int j = 0; j < 16; j++){
    int cc = j * 4 + w;
    int c = c0 + cc;
    float v = x[((size_t)(b * 512 + c)) * 4096 + p0 + pl];
    lt[pl][cc] = f2b(v * iv * g[c] * SQRT512);
  }
  __syncthreads();
  int pr = t >> 2, ch = (t & 3) * 16;
  u16* dst = xnT + (size_t)(pg0 + pr) * 512 + c0 + ch;
  *(short8*)dst = *(const short8*)&lt[pr][ch];
  *(short8*)(dst + 8) = *(const short8*)&lt[pr][ch + 8];
}

// ---- big TN GEMM: C[M][N] = A[M][K] @ BT[N][K]^T, bf16, m97 structure.
// 128x128 tile, BK=32, 4 waves x (64x64 quadrant, 4x4 16x16x32 frags).
template<int ADD_BIAS>
__global__ __launch_bounds__(256)
void gemm_big(const u16* __restrict__ Ab, long astr, int lda,
              const u16* __restrict__ Bb, long bstr, int ldb,
              u16* __restrict__ Cb, long cstr, int ldc,
              int K, const float* __restrict__ bias)
{
  const u16* A  = Ab + (size_t)blockIdx.z * astr;
  const u16* BT = Bb + (size_t)blockIdx.z * bstr;
  u16* C = Cb + (size_t)blockIdx.z * cstr;
  const int m0 = blockIdx.y * 128, n0 = blockIdx.x * 128;
  __shared__ u16 As[128 * 32];
  __shared__ u16 Bs[128 * 32];
  const int tid = threadIdx.x;
  const int srow = tid >> 2, scol = (tid & 3) * 8;   // staging: 64 rows per pass
  const u16* ag0 = A + (size_t)(m0 + srow) * lda + scol;
  const u16* ag1 = ag0 + (size_t)64 * lda;
  const u16* bg0 = BT + (size_t)(n0 + srow) * ldb + scol;
  const u16* bg1 = bg0 + (size_t)64 * ldb;
  u16* asl0 = As + tid * 8;        u16* asl1 = As + 2048 + tid * 8;
  u16* bsl0 = Bs + tid * 8;        u16* bsl1 = Bs + 2048 + tid * 8;
  const int lane = tid & 63, wid = tid >> 6;
  const int wr = (wid >> 1) * 64, wc = (wid & 1) * 64;
  const int fr = lane & 15, fq = lane >> 4;
  f32x4 acc[4][4] = {};
  for (int k0 = 0; k0 < K; k0 += 32){
    gl16(ag0 + k0, asl0);
    gl16(ag1 + k0, asl1);
    gl16(bg0 + k0, bsl0);
    gl16(bg1 + k0, bsl1);
    __syncthreads();
    short8 a[4], b[4];
    #pragma unroll
    for (int i = 0; i < 4; i++){
      a[i] = *(const short8*)(As + (wr + i * 16 + fr) * 32 + fq * 8);
      b[i] = *(const short8*)(Bs + (wc + i * 16 + fr) * 32 + fq * 8);
    }
    #pragma unroll
    for (int i = 0; i < 4; i++)
      #pragma unroll
      for (int j = 0; j < 4; j++)
        acc[i][j] = __builtin_amdgcn_mfma_f32_16x16x32_bf16(a[i], b[j], acc[i][j], 0, 0, 0);
    __syncthreads();
  }
  #pragma unroll
  for (int i = 0; i < 4; i++)
    #pragma unroll
    for (int j = 0; j < 4; j++)
      #pragma unroll
      for (int e = 0; e < 4; e++){
        int row = m0 + wr + i * 16 + fq * 4 + e;
        int col = n0 + wc + j * 16 + fr;
        float v = acc[i][j][e];
        if constexpr (ADD_BIAS) v += bias[col];
        C[(size_t)row * ldc + col] = f2b(v);
      }
}

// ---- q softmax over 64 contiguous cols of qT row-segment, /8, in place
__global__ __launch_bounds__(256)
void qsoftmax2(u16* __restrict__ qT){
  int idx = blockIdx.x * 256 + threadIdx.x;   // 32768*8
  u16* p = qT + (size_t)(idx >> 3) * 512 + (size_t)(idx & 7) * 64;
  float v[64], mx = -1e30f;
  #pragma unroll
  for (int j = 0; j < 8; j++){
    short8 t = *(const short8*)(p + j * 8);
    #pragma unroll
    for (int e = 0; e < 8; e++){ v[j * 8 + e] = b2f((u16)t[e]); mx = fmaxf(mx, v[j * 8 + e]); }
  }
  float s = 0.f;
  #pragma unroll
  for (int d = 0; d < 64; d++){ v[d] = __expf(v[d] - mx); s += v[d]; }
  float r = 1.f / (s * 8.0f);
  #pragma unroll
  for (int j = 0; j < 8; j++){
    short8 o;
    #pragma unroll
    for (int e = 0; e < 8; e++) o[e] = (short)f2b(v[j * 8 + e] * r);
    *(short8*)(p + j * 8) = o;
  }
}

// ---- k softmax over contiguous n=4096, one block per (b, c-row), in place
__global__ __launch_bounds__(256)
void ksoftmaxN(u16* __restrict__ kv){
  int bx = blockIdx.x;                       // 0..4095
  int b = bx >> 9, c = bx & 511;
  u16* kp = kv + (size_t)b * KV_B + (size_t)c * 4096;
  int tid = threadIdx.x;
  float v[16], mx = -1e30f;
  #pragma unroll
  for (int j = 0; j < 2; j++){
    short8 t = *(const short8*)(kp + j * 2048 + tid * 8);
    #pragma unroll
    for (int e = 0; e < 8; e++){ v[j * 8 + e] = b2f((u16)t[e]); mx = fmaxf(mx, v[j * 8 + e]); }
  }
  #pragma unroll
  for (int o = 32; o >= 1; o >>= 1) mx = fmaxf(mx, __shfl_xor(mx, o));
  __shared__ float redm[4], reds[4];
  if ((tid & 63) == 0) redm[tid >> 6] = mx;
  __syncthreads();
  mx = fmaxf(fmaxf(redm[0], redm[1]), fmaxf(redm[2], redm[3]));
  float s = 0.f;
  #pragma unroll
  for (int j = 0; j < 16; j++){ v[j] = __expf(v[j] - mx); s += v[j]; }
  #pragma unroll
  for (int o = 32; o >= 1; o >>= 1) s += __shfl_xor(s, o);
  if ((tid & 63) == 0) reds[tid >> 6] = s;
  __syncthreads();
  s = reds[0] + reds[1] + reds[2] + reds[3];
  float r = 1.f / s;
  #pragma unroll
  for (int j = 0; j < 2; j++){
    short8 o;
    #pragma unroll
    for (int e = 0; e < 8; e++) o[e] = (short)f2b(v[j * 8 + e] * r);
    *(short8*)(kp + j * 2048 + tid * 8) = o;
  }
}

// ---- small 64x64-tile TN GEMM. MODE 0: ctx split-K partials (f32).
//      MODE 1: attnT = qT(slice) @ ctxT^T (bf16).
template<int MODE>
__global__ __launch_bounds__(256)
void gemm_small(const u16* __restrict__ kv, const u16* __restrict__ qT,
                const u16* __restrict__ ctxT, float* __restrict__ P,
                u16* __restrict__ attnT)
{
  constexpr int K = (MODE == 0) ? 1024 : 64;
  const int z = blockIdx.z;
  const u16* A; const u16* BT; int lda, ldb, m0 = 0;
  if constexpr (MODE == 0){
    int bh = z >> 2, s = z & 3, b = bh >> 3, h = bh & 7;
    A  = kv + (size_t)b * KV_B + (size_t)(h * 64) * 4096 + s * 1024;
    BT = kv + (size_t)b * KV_B + (size_t)(512 + h * 64) * 4096 + s * 1024;
    lda = 4096; ldb = 4096;
  } else {
    int b = z >> 3, h = z & 7;
    A  = qT + (size_t)b * 4096 * 512 + h * 64;
    BT = ctxT + (size_t)z * 4096;
    lda = 512; ldb = 64;
    m0 = blockIdx.y * 64;
  }
  __shared__ u16 As[64 * 40];
  __shared__ u16 Bs[64 * 40];
  const int tid = threadIdx.x;
  const int wid = tid >> 6, lane = tid & 63;
  const int wr = (wid >> 1) * 32, wc = (wid & 1) * 32;
  const int lr = lane & 15, kb = lane >> 4;
  const int ar = tid >> 2, ac = (tid & 3) * 8;
  f32x4 acc[2][2] = {};
  for (int k0 = 0; k0 < K; k0 += 32){
    *(short8*)(As + ar * 40 + ac) = *(const short8*)(A + (size_t)(m0 + ar) * lda + k0 + ac);
    *(short8*)(Bs + ar * 40 + ac) = *(const short8*)(BT + (size_t)ar * ldb + k0 + ac);
    __syncthreads();
    short8 a0 = *(const short8*)(As + (wr +      lr) * 40 + kb * 8);
    short8 a1 = *(const short8*)(As + (wr + 16 + lr) * 40 + kb * 8);
    short8 b0 = *(const short8*)(Bs + (wc +      lr) * 40 + kb * 8);
    short8 b1 = *(const short8*)(Bs + (wc + 16 + lr) * 40 + kb * 8);
    acc[0][0] = __builtin_amdgcn_mfma_f32_16x16x32_bf16(a0, b0, acc[0][0], 0, 0, 0);
    acc[0][1] = __builtin_amdgcn_mfma_f32_16x16x32_bf16(a0, b1, acc[0][1], 0, 0, 0);
    acc[1][0] = __builtin_amdgcn_mfma_f32_16x16x32_bf16(a1, b0, acc[1][0], 0, 0, 0);
    acc[1][1] = __builtin_amdgcn_mfma_f32_16x16x32_bf16(a1, b1, acc[1][1], 0, 0, 0);
    __syncthreads();
  }
  #pragma unroll
  for (int mi = 0; mi < 2; mi++)
    #pragma unroll
    for (int ni = 0; ni < 2; ni++)
      #pragma unroll
      for (int j = 0; j < 4; j++){
        int row = m0 + wr + mi * 16 + kb * 4 + j;
        int col = wc + ni * 16 + lr;
        if constexpr (MODE == 0){
          P[(size_t)z * 4096 + (size_t)(row) * 64 + col] = acc[mi][ni][j];
        } else {
          attnT[(size_t)(z >> 3) * 4096 * 512 + (size_t)row * 512 + (z & 7) * 64 + col]
            = f2b(acc[mi][ni][j]);
        }
      }
}

// ---- reduce 4 ctx split partials [d][e] f32 -> ctxT [e][d] bf16
__global__ __launch_bounds__(256)
void kreduce(const float* __restrict__ P, u16* __restrict__ ctxT){
  int o = blockIdx.x * 256 + threadIdx.x;    // 64*4096
  int bh = o >> 12, r = o & 4095, e = r >> 6, d = r & 63;
  const float* p = P + ((size_t)bh << 14) + (d << 6) + e;
  float s = p[0] + p[4096] + p[8192] + p[12288];
  ctxT[((size_t)bh << 12) + r] = f2b(s);
}

// ---- per-row (pixel) sumsq of out2T [n][512] -> inv
__global__ __launch_bounds__(256)
void ksumsq2(const u16* __restrict__ o2, float* __restrict__ inv){
  int t = threadIdx.x;
  int row = blockIdx.x * 32 + (t >> 3);
  const u16* p = o2 + (size_t)row * 512 + (size_t)(t & 7) * 64;
  float s = 0.f;
  #pragma unroll
  for (int j = 0; j < 8; j++){
    short8 v = *(const short8*)(p + j * 8);
    #pragma unroll
    for (int e = 0; e < 8; e++){ float f = b2f((u16)v[e]); s += f * f; }
  }
  s += __shfl_xor(s, 1); s += __shfl_xor(s, 2); s += __shfl_xor(s, 4);
  if ((t & 7) == 0) inv[row] = rsqrtf(s + 1e-12f);
}

// ---- rms2 + transpose: out2T [n][c] bf16 -> d_out [c][p] f32 (64x64 tiles)
__global__ __launch_bounds__(256)
void rms2T(const u16* __restrict__ o2, const float* __restrict__ g,
           const float* __restrict__ inv, float* __restrict__ out){
  __shared__ float lt[64][68];
  int t = threadIdx.x;
  int pg0 = blockIdx.x * 64, c0 = blockIdx.y * 64;
  int b = pg0 >> 12, p0 = pg0 & 4095;
  int cl = t & 63, w = t >> 6;
  float gf = g[c0 + cl] * SQRT512;
  #pragma unroll
  for (int j = 0; j < 16; j++){
    int p = j * 4 + w;
    float v = b2f(o2[(size_t)(pg0 + p) * 512 + c0 + cl]) * inv[pg0 + p] * gf;
    lt[cl][p] = v;
  }
  __syncthreads();
  int cr = t >> 2, pch = (t & 3) * 16;
  float* dst = out + ((size_t)(b * 512 + c0 + cr)) * 4096 + p0 + pch;
  const float* src = &lt[cr][pch];
  *(f32x4*)(dst +  0) = *(const f32x4*)(src +  0);
  *(f32x4*)(dst +  4) = *(const f32x4*)(src +  4);
  *(f32x4*)(dst +  8) = *(const f32x4*)(src +  8);
  *(f32x4*)(dst + 12) = *(const f32x4*)(src + 12);
}

extern "C" void kernel_launch(void* const* d_in, const int* in_sizes, int n_in,
                              void* d_out, int out_size, void* d_ws, size_t ws_size,
                              hipStream_t stream)
{
  (void)in_sizes; (void)n_in; (void)out_size; (void)ws_size;
  const float* x    = (const float*)d_in[0];
  const float* g1   = (const float*)d_in[1];
  const float* wqkv = (const float*)d_in[2];
  const float* wout = (const float*)d_in[3];
  const float* bout = (const float*)d_in[4];
  const float* g2   = (const float*)d_in[5];
  float* out = (float*)d_out;
  char* ws = (char*)d_ws;

  u16*   xnT   = (u16*)(ws);                          // S1
  float* P     = (float*)(ws);                        // S1 (after xnT dead)
  u16*   attnT = (u16*)(ws);                          // S1 (after P dead)
  u16*   qT    = (u16*)(ws + (size_t)33554432);       // S2
  u16*   out2T = (u16*)(ws + (size_t)33554432);       // S2 (after qT dead)
  u16*   kv    = (u16*)(ws + (size_t)67108864);       // S3
  u16*   wbf   = (u16*)(ws + (size_t)134217728);      // E: wq(512 rows)+wkv(1024 rows)
  u16*   ctxT  = (u16*)(ws + (size_t)134217728);      // E (after wq/wkv dead)
  u16*   wkvbf = wbf + (size_t)512 * 512;
  u16*   woutbf= (u16*)(ws + (size_t)135790592);
  float* inv   = (float*)(ws + (size_t)136314880);    // F (reused for rms2)

  // 0) weights -> bf16
  kcvt<<<768, 256, 0, stream>>>(wqkv, wbf);
  kcvt<<<256, 256, 0, stream>>>(wout, woutbf);
  // 1) rms1: sumsq + normalize-transpose -> xnT [n][c]
  ksumsq<<<512, 256, 0, stream>>>(x, inv);
  knormT<<<dim3(512, 8), 256, 0, stream>>>(x, g1, inv, xnT);
  // 2) qT = xnT @ Wq^T   (M=32768,N=512,K=512)
  gemm_big<0><<<dim3(4, 256, 1), 256, 0, stream>>>(xnT, 0, 512, wbf, 0, 512,
                                                   qT, 0, 512, 512, nullptr);
  //    kv_b = Wkv @ xn_b (per batch: M=1024,N=4096,K=512), C row-major [c][n]
  gemm_big<0><<<dim3(32, 8, 8), 256, 0, stream>>>(wkvbf, 0, 512,
                                                  xnT, (long)4096 * 512, 512,
                                                  kv, (long)KV_B, 4096, 512, nullptr);
  // 3) softmaxes
  qsoftmax2<<<1024, 256, 0, stream>>>(qT);
  ksoftmaxN<<<4096, 256, 0, stream>>>(kv);
  // 4) ctx split-K partials + reduce -> ctxT [e][d]
  gemm_small<0><<<dim3(1, 1, 256), 256, 0, stream>>>(kv, qT, ctxT, P, attnT);
  kreduce<<<1024, 256, 0, stream>>>(P, ctxT);
  // 5) attnT = qT @ ctxT^T per (b,h)  (M=4096,N=64,K=64)
  gemm_small<1><<<dim3(1, 64, 64), 256, 0, stream>>>(kv, qT, ctxT, P, attnT);
  // 6) out2T = attnT @ Wout^T + bias  (M=32768,N=512,K=512)
  gemm_big<1><<<dim3(4, 256, 1), 256, 0, stream>>>(attnT, 0, 512, woutbf, 0, 512,
                                                   out2T, 0, 512, 512, bout);
  // 7) rms2: row sumsq + normalize-transpose -> d_out [c][p] f32
  ksumsq2<<<1024, 256, 0, stream>>>(out2T, inv);
  rms2T<<<dim3(512, 8), 256, 0, stream>>>(out2T, g2, inv, out);
}

// Round 4
// 273.433 us; speedup vs baseline: 1.7905x; 1.0315x over previous
//
#include <hip/hip_runtime.h>

// LinearAttention on MI355X — round 4: BK=64 gemm_big + fused q-softmax epilogue.
// Layouts: xnT[n][c], qT[n][512], kv[b][1024][n], ctxT[bh][e][d], attnT[n][512],
//          out2T[n][512]. rms1/rms2 do the NCHW<->N,C transposes via LDS tiles.
// ws: S1=0(33.5M: xnT->P->attnT) S2=33.5M(qT->out2T) S3=67.1M(kv)
//     E=134217728(w_bf; reused for ctxT) F=136314880(inv) ~136.4MB

typedef unsigned short u16;
typedef __attribute__((ext_vector_type(8))) short short8;
typedef __attribute__((ext_vector_type(4))) short short4_t;
typedef __attribute__((ext_vector_type(4))) float f32x4;

static constexpr size_t XN_B = (size_t)512 * 4096;    // per-batch elems of [512][4096]
static constexpr size_t KV_B = (size_t)1024 * 4096;   // per-batch elems of kv
static constexpr float SQRT512 = 22.62741699796952f;

typedef const __attribute__((address_space(1))) unsigned int gu32;
typedef __attribute__((address_space(3))) unsigned int lu32;

__device__ __forceinline__ float b2f(u16 u){
  union { unsigned u; float f; } x; x.u = ((unsigned)u) << 16; return x.f;
}
__device__ __forceinline__ u16 f2b(float f){
  union { float f; unsigned u; } x; x.f = f;
  unsigned r = x.u + 0x7FFFu + ((x.u >> 16) & 1u);   // RNE
  return (u16)(r >> 16);
}
__device__ __forceinline__ void gl16(const u16* g, u16* l){
  __builtin_amdgcn_global_load_lds((gu32*)g, (lu32*)l, 16, 0, 0);
}

// ---- f32 -> bf16 weight convert, both weights in one launch (768+256 blocks)
__global__ __launch_bounds__(256)
void kcvt(const float* __restrict__ wqkv, const float* __restrict__ wout,
          u16* __restrict__ dq, u16* __restrict__ dо){
  size_t i = ((size_t)blockIdx.x * 256 + threadIdx.x) * 4;
  const float* src; u16* dst; size_t off;
  if (i < (size_t)786432){ src = wqkv; dst = dq; off = i; }
  else { src = wout; dst = dо; off = i - 786432; }
  f32x4 v = *(const f32x4*)(src + off);
  short4_t o;
  #pragma unroll
  for (int j = 0; j < 4; j++) o[j] = (short)f2b(v[j]);
  *(short4_t*)(dst + off) = o;
}

// ---- per-pixel sumsq over 512 channels of x [b][c][p] f32 -> inv
__global__ __launch_bounds__(256)
void ksumsq(const float* __restrict__ src, float* __restrict__ inv){
  int tid = threadIdx.x;
  int px = tid & 63, chunk = tid >> 6;
  int pg = blockIdx.x * 64 + px;
  int b = pg >> 12, p = pg & 4095;
  const float* sp = src + (size_t)b * XN_B + p;
  float s = 0.f;
  #pragma unroll 4
  for (int c = chunk * 128; c < chunk * 128 + 128; ++c){
    float v = sp[(size_t)c * 4096]; s += v * v;
  }
  __shared__ float red[256];
  red[tid] = s;
  __syncthreads();
  if (chunk == 0){
    float t = red[px] + red[px + 64] + red[px + 128] + red[px + 192];
    inv[pg] = rsqrtf(t + 1e-12f);
  }
}

// ---- rms1 + transpose: x [c][p] f32 -> xnT [p][c] bf16 (64x64 tiles)
__global__ __launch_bounds__(256)
void knormT(const float* __restrict__ x, const float* __restrict__ g,
            const float* __restrict__ inv, u16* __restrict__ xnT){
  __shared__ u16 lt[64][72];
  int t = threadIdx.x;
  int pg0 = blockIdx.x * 64, c0 = blockIdx.y * 64;
  int b = pg0 >> 12, p0 = pg0 & 4095;
  int pl = t & 63, w = t >> 6;
  float iv = inv[pg0 + pl];
  #pragma unroll
  for (int j = 0; j < 16; j++){
    int cc = j * 4 + w;
    int c = c0 + cc;
    float v = x[((size_t)(b * 512 + c)) * 4096 + p0 + pl];
    lt[pl][cc] = f2b(v * iv * g[c] * SQRT512);
  }
  __syncthreads();
  int pr = t >> 2, ch = (t & 3) * 16;
  u16* dst = xnT + (size_t)(pg0 + pr) * 512 + c0 + ch;
  *(short8*)dst = *(const short8*)&lt[pr][ch];
  *(short8*)(dst + 8) = *(const short8*)&lt[pr][ch + 8];
}

// ---- big TN GEMM: C[M][N] = A[M][K] @ BT[N][K]^T, bf16, 128^2 tile, BK=64.
// 4 waves x (64x64 quadrant, 4x4 16x16x32 frags), global_load_lds staging.
// SMAX: per-row softmax over the wave's 64-col quadrant (= one head), then /8.
template<int ADD_BIAS, int SMAX>
__global__ __launch_bounds__(256)
void gemm_big(const u16* __restrict__ Ab, long astr, int lda,
              const u16* __restrict__ Bb, long bstr, int ldb,
              u16* __restrict__ Cb, long cstr, int ldc,
              int K, const float* __restrict__ bias)
{
  const u16* A  = Ab + (size_t)blockIdx.z * astr;
  const u16* BT = Bb + (size_t)blockIdx.z * bstr;
  u16* C = Cb + (size_t)blockIdx.z * cstr;
  const int m0 = blockIdx.y * 128, n0 = blockIdx.x * 128;
  __shared__ u16 As[128 * 64];
  __shared__ u16 Bs[128 * 64];
  const int tid = threadIdx.x;
  const int srow = tid >> 3, scol = (tid & 7) * 8;   // 32 rows per chunk, 4 chunks
  const u16* ag = A + (size_t)(m0 + srow) * lda + scol;
  const u16* bg = BT + (size_t)(n0 + srow) * ldb + scol;
  u16* asl = As + tid * 8;
  u16* bsl = Bs + tid * 8;
  const int lane = tid & 63, wid = tid >> 6;
  const int wr = (wid >> 1) * 64, wc = (wid & 1) * 64;
  const int fr = lane & 15, fq = lane >> 4;
  f32x4 acc[4][4] = {};
  for (int k0 = 0; k0 < K; k0 += 64){
    #pragma unroll
    for (int c = 0; c < 4; c++){
      gl16(ag + (size_t)c * 32 * lda + k0, asl + c * 2048);
      gl16(bg + (size_t)c * 32 * ldb + k0, bsl + c * 2048);
    }
    __syncthreads();
    #pragma unroll
    for (int ks = 0; ks < 2; ks++){
      short8 a[4], b[4];
      #pragma unroll
      for (int i = 0; i < 4; i++){
        a[i] = *(const short8*)(As + (wr + i * 16 + fr) * 64 + ks * 32 + fq * 8);
        b[i] = *(const short8*)(Bs + (wc + i * 16 + fr) * 64 + ks * 32 + fq * 8);
      }
      #pragma unroll
      for (int i = 0; i < 4; i++)
        #pragma unroll
        for (int j = 0; j < 4; j++)
          acc[i][j] = __builtin_amdgcn_mfma_f32_16x16x32_bf16(a[i], b[j], acc[i][j], 0, 0, 0);
    }
    __syncthreads();
  }
  if constexpr (SMAX){
    // softmax over each row's 64-col quadrant: reduce across fr (16 lanes) x 4 j-frags
    #pragma unroll
    for (int i = 0; i < 4; i++)
      #pragma unroll
      for (int e = 0; e < 4; e++){
        float mx = fmaxf(fmaxf(acc[i][0][e], acc[i][1][e]),
                         fmaxf(acc[i][2][e], acc[i][3][e]));
        mx = fmaxf(mx, __shfl_xor(mx, 1));
        mx = fmaxf(mx, __shfl_xor(mx, 2));
        mx = fmaxf(mx, __shfl_xor(mx, 4));
        mx = fmaxf(mx, __shfl_xor(mx, 8));
        float p0 = __expf(acc[i][0][e] - mx);
        float p1 = __expf(acc[i][1][e] - mx);
        float p2 = __expf(acc[i][2][e] - mx);
        float p3 = __expf(acc[i][3][e] - mx);
        float s = p0 + p1 + p2 + p3;
        s += __shfl_xor(s, 1);
        s += __shfl_xor(s, 2);
        s += __shfl_xor(s, 4);
        s += __shfl_xor(s, 8);
        float r = 1.f / (s * 8.0f);    // SCALE = sqrt(64) = 8
        acc[i][0][e] = p0 * r; acc[i][1][e] = p1 * r;
        acc[i][2][e] = p2 * r; acc[i][3][e] = p3 * r;
      }
  }
  #pragma unroll
  for (int i = 0; i < 4; i++)
    #pragma unroll
    for (int j = 0; j < 4; j++)
      #pragma unroll
      for (int e = 0; e < 4; e++){
        int row = m0 + wr + i * 16 + fq * 4 + e;
        int col = n0 + wc + j * 16 + fr;
        float v = acc[i][j][e];
        if constexpr (ADD_BIAS) v += bias[col];
        C[(size_t)row * ldc + col] = f2b(v);
      }
}

// ---- k softmax over contiguous n=4096, one block per (b, c-row), in place
__global__ __launch_bounds__(256)
void ksoftmaxN(u16* __restrict__ kv){
  int bx = blockIdx.x;                       // 0..4095
  int b = bx >> 9, c = bx & 511;
  u16* kp = kv + (size_t)b * KV_B + (size_t)c * 4096;
  int tid = threadIdx.x;
  float v[16], mx = -1e30f;
  #pragma unroll
  for (int j = 0; j < 2; j++){
    short8 t = *(const short8*)(kp + j * 2048 + tid * 8);
    #pragma unroll
    for (int e = 0; e < 8; e++){ v[j * 8 + e] = b2f((u16)t[e]); mx = fmaxf(mx, v[j * 8 + e]); }
  }
  #pragma unroll
  for (int o = 32; o >= 1; o >>= 1) mx = fmaxf(mx, __shfl_xor(mx, o));
  __shared__ float redm[4], reds[4];
  if ((tid & 63) == 0) redm[tid >> 6] = mx;
  __syncthreads();
  mx = fmaxf(fmaxf(redm[0], redm[1]), fmaxf(redm[2], redm[3]));
  float s = 0.f;
  #pragma unroll
  for (int j = 0; j < 16; j++){ v[j] = __expf(v[j] - mx); s += v[j]; }
  #pragma unroll
  for (int o = 32; o >= 1; o >>= 1) s += __shfl_xor(s, o);
  if ((tid & 63) == 0) reds[tid >> 6] = s;
  __syncthreads();
  s = reds[0] + reds[1] + reds[2] + reds[3];
  float r = 1.f / s;
  #pragma unroll
  for (int j = 0; j < 2; j++){
    short8 o;
    #pragma unroll
    for (int e = 0; e < 8; e++) o[e] = (short)f2b(v[j * 8 + e] * r);
    *(short8*)(kp + j * 2048 + tid * 8) = o;
  }
}

// ---- small 64x64-tile TN GEMM. MODE 0: ctx split-K partials (f32).
//      MODE 1: attnT = qT(slice) @ ctxT^T (bf16).
template<int MODE>
__global__ __launch_bounds__(256)
void gemm_small(const u16* __restrict__ kv, const u16* __restrict__ qT,
                const u16* __restrict__ ctxT, float* __restrict__ P,
                u16* __restrict__ attnT)
{
  constexpr int K = (MODE == 0) ? 1024 : 64;
  const int z = blockIdx.z;
  const u16* A; const u16* BT; int lda, ldb, m0 = 0;
  if constexpr (MODE == 0){
    int bh = z >> 2, s = z & 3, b = bh >> 3, h = bh & 7;
    A  = kv + (size_t)b * KV_B + (size_t)(h * 64) * 4096 + s * 1024;
    BT = kv + (size_t)b * KV_B + (size_t)(512 + h * 64) * 4096 + s * 1024;
    lda = 4096; ldb = 4096;
  } else {
    int b = z >> 3, h = z & 7;
    A  = qT + (size_t)b * 4096 * 512 + h * 64;
    BT = ctxT + (size_t)z * 4096;
    lda = 512; ldb = 64;
    m0 = blockIdx.y * 64;
  }
  __shared__ u16 As[64 * 40];
  __shared__ u16 Bs[64 * 40];
  const int tid = threadIdx.x;
  const int wid = tid >> 6, lane = tid & 63;
  const int wr = (wid >> 1) * 32, wc = (wid & 1) * 32;
  const int lr = lane & 15, kb = lane >> 4;
  const int ar = tid >> 2, ac = (tid & 3) * 8;
  f32x4 acc[2][2] = {};
  for (int k0 = 0; k0 < K; k0 += 32){
    *(short8*)(As + ar * 40 + ac) = *(const short8*)(A + (size_t)(m0 + ar) * lda + k0 + ac);
    *(short8*)(Bs + ar * 40 + ac) = *(const short8*)(BT + (size_t)ar * ldb + k0 + ac);
    __syncthreads();
    short8 a0 = *(const short8*)(As + (wr +      lr) * 40 + kb * 8);
    short8 a1 = *(const short8*)(As + (wr + 16 + lr) * 40 + kb * 8);
    short8 b0 = *(const short8*)(Bs + (wc +      lr) * 40 + kb * 8);
    short8 b1 = *(const short8*)(Bs + (wc + 16 + lr) * 40 + kb * 8);
    acc[0][0] = __builtin_amdgcn_mfma_f32_16x16x32_bf16(a0, b0, acc[0][0], 0, 0, 0);
    acc[0][1] = __builtin_amdgcn_mfma_f32_16x16x32_bf16(a0, b1, acc[0][1], 0, 0, 0);
    acc[1][0] = __builtin_amdgcn_mfma_f32_16x16x32_bf16(a1, b0, acc[1][0], 0, 0, 0);
    acc[1][1] = __builtin_amdgcn_mfma_f32_16x16x32_bf16(a1, b1, acc[1][1], 0, 0, 0);
    __syncthreads();
  }
  #pragma unroll
  for (int mi = 0; mi < 2; mi++)
    #pragma unroll
    for (int ni = 0; ni < 2; ni++)
      #pragma unroll
      for (int j = 0; j < 4; j++){
        int row = m0 + wr + mi * 16 + kb * 4 + j;
        int col = wc + ni * 16 + lr;
        if constexpr (MODE == 0){
          P[(size_t)z * 4096 + (size_t)(row) * 64 + col] = acc[mi][ni][j];
        } else {
          attnT[(size_t)(z >> 3) * 4096 * 512 + (size_t)row * 512 + (z & 7) * 64 + col]
            = f2b(acc[mi][ni][j]);
        }
      }
}

// ---- reduce 4 ctx split partials [d][e] f32 -> ctxT [e][d] bf16
__global__ __launch_bounds__(256)
void kreduce(const float* __restrict__ P, u16* __restrict__ ctxT){
  int o = blockIdx.x * 256 + threadIdx.x;    // 64*4096
  int bh = o >> 12, r = o & 4095, e = r >> 6, d = r & 63;
  const float* p = P + ((size_t)bh << 14) + (d << 6) + e;
  float s = p[0] + p[4096] + p[8192] + p[12288];
  ctxT[((size_t)bh << 12) + r] = f2b(s);
}

// ---- per-row (pixel) sumsq of out2T [n][512] -> inv
__global__ __launch_bounds__(256)
void ksumsq2(const u16* __restrict__ o2, float* __restrict__ inv){
  int t = threadIdx.x;
  int row = blockIdx.x * 32 + (t >> 3);
  const u16* p = o2 + (size_t)row * 512 + (size_t)(t & 7) * 64;
  float s = 0.f;
  #pragma unroll
  for (int j = 0; j < 8; j++){
    short8 v = *(const short8*)(p + j * 8);
    #pragma unroll
    for (int e = 0; e < 8; e++){ float f = b2f((u16)v[e]); s += f * f; }
  }
  s += __shfl_xor(s, 1); s += __shfl_xor(s, 2); s += __shfl_xor(s, 4);
  if ((t & 7) == 0) inv[row] = rsqrtf(s + 1e-12f);
}

// ---- rms2 + transpose: out2T [n][c] bf16 -> d_out [c][p] f32 (64x64 tiles)
__global__ __launch_bounds__(256)
void rms2T(const u16* __restrict__ o2, const float* __restrict__ g,
           const float* __restrict__ inv, float* __restrict__ out){
  __shared__ float lt[64][68];
  int t = threadIdx.x;
  int pg0 = blockIdx.x * 64, c0 = blockIdx.y * 64;
  int b = pg0 >> 12, p0 = pg0 & 4095;
  int cl = t & 63, w = t >> 6;
  float gf = g[c0 + cl] * SQRT512;
  #pragma unroll
  for (int j = 0; j < 16; j++){
    int p = j * 4 + w;
    float v = b2f(o2[(size_t)(pg0 + p) * 512 + c0 + cl]) * inv[pg0 + p] * gf;
    lt[cl][p] = v;
  }
  __syncthreads();
  int cr = t >> 2, pch = (t & 3) * 16;
  float* dst = out + ((size_t)(b * 512 + c0 + cr)) * 4096 + p0 + pch;
  const float* src = &lt[cr][pch];
  *(f32x4*)(dst +  0) = *(const f32x4*)(src +  0);
  *(f32x4*)(dst +  4) = *(const f32x4*)(src +  4);
  *(f32x4*)(dst +  8) = *(const f32x4*)(src +  8);
  *(f32x4*)(dst + 12) = *(const f32x4*)(src + 12);
}

extern "C" void kernel_launch(void* const* d_in, const int* in_sizes, int n_in,
                              void* d_out, int out_size, void* d_ws, size_t ws_size,
                              hipStream_t stream)
{
  (void)in_sizes; (void)n_in; (void)out_size; (void)ws_size;
  const float* x    = (const float*)d_in[0];
  const float* g1   = (const float*)d_in[1];
  const float* wqkv = (const float*)d_in[2];
  const float* wout = (const float*)d_in[3];
  const float* bout = (const float*)d_in[4];
  const float* g2   = (const float*)d_in[5];
  float* out = (float*)d_out;
  char* ws = (char*)d_ws;

  u16*   xnT   = (u16*)(ws);                          // S1
  float* P     = (float*)(ws);                        // S1 (after xnT dead)
  u16*   attnT = (u16*)(ws);                          // S1 (after P dead)
  u16*   qT    = (u16*)(ws + (size_t)33554432);       // S2
  u16*   out2T = (u16*)(ws + (size_t)33554432);       // S2 (after qT dead)
  u16*   kv    = (u16*)(ws + (size_t)67108864);       // S3
  u16*   wbf   = (u16*)(ws + (size_t)134217728);      // E: wq(512 rows)+wkv(1024 rows)
  u16*   ctxT  = (u16*)(ws + (size_t)134217728);      // E (after wq/wkv dead)
  u16*   wkvbf = wbf + (size_t)512 * 512;
  u16*   woutbf= (u16*)(ws + (size_t)135790592);
  float* inv   = (float*)(ws + (size_t)136314880);    // F (reused for rms2)

  // 0) weights -> bf16 (single launch)
  kcvt<<<1024, 256, 0, stream>>>(wqkv, wout, wbf, woutbf);
  // 1) rms1: sumsq + normalize-transpose -> xnT [n][c]
  ksumsq<<<512, 256, 0, stream>>>(x, inv);
  knormT<<<dim3(512, 8), 256, 0, stream>>>(x, g1, inv, xnT);
  // 2) qT = softmax_d(xnT @ Wq^T)/8   (M=32768,N=512,K=512; fused q-softmax)
  gemm_big<0, 1><<<dim3(4, 256, 1), 256, 0, stream>>>(xnT, 0, 512, wbf, 0, 512,
                                                      qT, 0, 512, 512, nullptr);
  //    kv_b = Wkv @ xn_b (per batch: M=1024,N=4096,K=512), C row-major [c][n]
  gemm_big<0, 0><<<dim3(32, 8, 8), 256, 0, stream>>>(wkvbf, 0, 512,
                                                     xnT, (long)4096 * 512, 512,
                                                     kv, (long)KV_B, 4096, 512, nullptr);
  // 3) k softmax over n
  ksoftmaxN<<<4096, 256, 0, stream>>>(kv);
  // 4) ctx split-K partials + reduce -> ctxT [e][d]
  gemm_small<0><<<dim3(1, 1, 256), 256, 0, stream>>>(kv, qT, ctxT, P, attnT);
  kreduce<<<1024, 256, 0, stream>>>(P, ctxT);
  // 5) attnT = qT @ ctxT^T per (b,h)  (M=4096,N=64,K=64)
  gemm_small<1><<<dim3(1, 64, 64), 256, 0, stream>>>(kv, qT, ctxT, P, attnT);
  // 6) out2T = attnT @ Wout^T + bias  (M=32768,N=512,K=512)
  gemm_big<1, 0><<<dim3(4, 256, 1), 256, 0, stream>>>(attnT, 0, 512, woutbf, 0, 512,
                                                      out2T, 0, 512, 512, bout);
  // 7) rms2: row sumsq + normalize-transpose -> d_out [c][p] f32
  ksumsq2<<<1024, 256, 0, stream>>>(out2T, inv);
  rms2T<<<dim3(512, 8), 256, 0, stream>>>(out2T, g2, inv, out);
}

// Round 5
// 248.463 us; speedup vs baseline: 1.9704x; 1.1005x over previous
//
#include <hip/hip_runtime.h>

// LinearAttention on MI355X — round 5:
//  gemm_big: BK=64, both-sides chunk-XOR swizzle (2-way conflicts), LDS double
//  buffer with counted s_waitcnt vmcnt(8) + raw s_barrier (loads stay in flight
//  across barriers); k-softmax fused into ctx GEMM via kstats.
// Layouts: xnT[n][c], qT[n][512], kv[b][1024][n], ctxT[bh][e][d], attnT[n][512],
//          out2T[n][512].
// ws: S1=0(33.5M: xnT->P->attnT) S2=33.5M(qT->out2T) S3=67.1M(kv)
//     E=134217728: wbf(1.5M, later ctxT 512K + kstats 32K) wout_bf@135790592
//     F=136314880: inv (128K)

typedef unsigned short u16;
typedef __attribute__((ext_vector_type(8))) short short8;
typedef __attribute__((ext_vector_type(4))) short short4_t;
typedef __attribute__((ext_vector_type(4))) float f32x4;

static constexpr size_t XN_B = (size_t)512 * 4096;
static constexpr size_t KV_B = (size_t)1024 * 4096;
static constexpr float SQRT512 = 22.62741699796952f;

typedef const __attribute__((address_space(1))) unsigned int gu32;
typedef __attribute__((address_space(3))) unsigned int lu32;

__device__ __forceinline__ float b2f(u16 u){
  union { unsigned u; float f; } x; x.u = ((unsigned)u) << 16; return x.f;
}
__device__ __forceinline__ u16 f2b(float f){
  union { float f; unsigned u; } x; x.f = f;
  unsigned r = x.u + 0x7FFFu + ((x.u >> 16) & 1u);   // RNE
  return (u16)(r >> 16);
}
__device__ __forceinline__ void gl16(const u16* g, u16* l){
  __builtin_amdgcn_global_load_lds((gu32*)g, (lu32*)l, 16, 0, 0);
}

// ---- f32 -> bf16 weight convert (both weights, one launch)
__global__ __launch_bounds__(256)
void kcvt(const float* __restrict__ wqkv, const float* __restrict__ wout,
          u16* __restrict__ dq, u16* __restrict__ dw){
  size_t i = ((size_t)blockIdx.x * 256 + threadIdx.x) * 4;
  const float* src; u16* dst; size_t off;
  if (i < (size_t)786432){ src = wqkv; dst = dq; off = i; }
  else { src = wout; dst = dw; off = i - 786432; }
  f32x4 v = *(const f32x4*)(src + off);
  short4_t o;
  #pragma unroll
  for (int j = 0; j < 4; j++) o[j] = (short)f2b(v[j]);
  *(short4_t*)(dst + off) = o;
}

// ---- per-pixel sumsq over 512 channels of x [b][c][p] f32 -> inv
__global__ __launch_bounds__(256)
void ksumsq(const float* __restrict__ src, float* __restrict__ inv){
  int tid = threadIdx.x;
  int px = tid & 63, chunk = tid >> 6;
  int pg = blockIdx.x * 64 + px;
  int b = pg >> 12, p = pg & 4095;
  const float* sp = src + (size_t)b * XN_B + p;
  float s = 0.f;
  #pragma unroll 4
  for (int c = chunk * 128; c < chunk * 128 + 128; ++c){
    float v = sp[(size_t)c * 4096]; s += v * v;
  }
  __shared__ float red[256];
  red[tid] = s;
  __syncthreads();
  if (chunk == 0){
    float t = red[px] + red[px + 64] + red[px + 128] + red[px + 192];
    inv[pg] = rsqrtf(t + 1e-12f);
  }
}

// ---- rms1 + transpose: x [c][p] f32 -> xnT [p][c] bf16 (64x64 tiles)
__global__ __launch_bounds__(256)
void knormT(const float* __restrict__ x, const float* __restrict__ g,
            const float* __restrict__ inv, u16* __restrict__ xnT){
  __shared__ u16 lt[64][72];
  int t = threadIdx.x;
  int pg0 = blockIdx.x * 64, c0 = blockIdx.y * 64;
  int b = pg0 >> 12, p0 = pg0 & 4095;
  int pl = t & 63, w = t >> 6;
  float iv = inv[pg0 + pl];
  #pragma unroll
  for (int j = 0; j < 16; j++){
    int cc = j * 4 + w;
    int c = c0 + cc;
    float v = x[((size_t)(b * 512 + c)) * 4096 + p0 + pl];
    lt[pl][cc] = f2b(v * iv * g[c] * SQRT512);
  }
  __syncthreads();
  int pr = t >> 2, ch = (t & 3) * 16;
  u16* dst = xnT + (size_t)(pg0 + pr) * 512 + c0 + ch;
  *(short8*)dst = *(const short8*)&lt[pr][ch];
  *(short8*)(dst + 8) = *(const short8*)&lt[pr][ch + 8];
}

// ---- big TN GEMM: C[M][N] = A[M][K=512] @ BT[N][K]^T, bf16, 128^2 tile, BK=64.
// Double-buffered LDS, counted vmcnt, chunk-XOR swizzle on both sides.
// SMAX: per-row softmax over the wave's 64-col quadrant (= one head), then /8.
template<int ADD_BIAS, int SMAX>
__global__ __launch_bounds__(256)
void gemm_big(const u16* __restrict__ Ab, long astr, int lda,
              const u16* __restrict__ Bb, long bstr, int ldb,
              u16* __restrict__ Cb, long cstr, int ldc,
              const float* __restrict__ bias)
{
  constexpr int NT = 8;                 // K=512 / BK=64
  const u16* A  = Ab + (size_t)blockIdx.z * astr;
  const u16* BT = Bb + (size_t)blockIdx.z * bstr;
  u16* C = Cb + (size_t)blockIdx.z * cstr;
  const int m0 = blockIdx.y * 128, n0 = blockIdx.x * 128;
  __shared__ u16 As[2][128 * 64];
  __shared__ u16 Bs[2][128 * 64];
  const int tid = threadIdx.x;
  const int srow0 = tid >> 3;           // row within each 32-row staging group
  const int schunk = tid & 7;           // 16B chunk slot within 128B row
  const int lane = tid & 63, wid = tid >> 6;
  const int wr = (wid >> 1) * 64, wc = (wid & 1) * 64;
  const int fr = lane & 15, fq = lane >> 4;
  f32x4 acc[4][4] = {};

  // stage tile t (k0 = t*64) into buffer s; LDS dest linear, global src chunk
  // pre-swizzled so that LDS slot c of row r holds global chunk c^(r&7).
  auto STAGE = [&](int s, int t){
    const int k0 = t * 64;
    #pragma unroll
    for (int r = 0; r < 4; r++){
      int row = r * 32 + srow0;
      int gj = (schunk ^ (row & 7)) * 8;
      gl16(A  + (size_t)(m0 + row) * lda + k0 + gj, &As[s][0] + r * 2048 + tid * 8);
      gl16(BT + (size_t)(n0 + row) * ldb + k0 + gj, &Bs[s][0] + r * 2048 + tid * 8);
    }
  };

  STAGE(0, 0);
  int cur = 0;
  for (int t = 0; t < NT; t++){
    if (t + 1 < NT){
      STAGE(cur ^ 1, t + 1);
      asm volatile("s_waitcnt vmcnt(8)" ::: "memory");   // tile t's 8 loads done
    } else {
      asm volatile("s_waitcnt vmcnt(0)" ::: "memory");
    }
    __builtin_amdgcn_s_barrier();
    __builtin_amdgcn_sched_barrier(0);
    #pragma unroll
    for (int ks = 0; ks < 2; ks++){
      short8 a[4], b[4];
      #pragma unroll
      for (int i = 0; i < 4; i++){
        int ra = wr + i * 16 + fr;
        a[i] = *(const short8*)(&As[cur][0] + ra * 64 + ((ks * 4 + fq) ^ (ra & 7)) * 8);
        int rb = wc + i * 16 + fr;
        b[i] = *(const short8*)(&Bs[cur][0] + rb * 64 + ((ks * 4 + fq) ^ (rb & 7)) * 8);
      }
      #pragma unroll
      for (int i = 0; i < 4; i++)
        #pragma unroll
        for (int j = 0; j < 4; j++)
          acc[i][j] = __builtin_amdgcn_mfma_f32_16x16x32_bf16(a[i], b[j], acc[i][j], 0, 0, 0);
    }
    __builtin_amdgcn_sched_barrier(0);
    __builtin_amdgcn_s_barrier();
    cur ^= 1;
  }

  if constexpr (SMAX){
    #pragma unroll
    for (int i = 0; i < 4; i++)
      #pragma unroll
      for (int e = 0; e < 4; e++){
        float mx = fmaxf(fmaxf(acc[i][0][e], acc[i][1][e]),
                         fmaxf(acc[i][2][e], acc[i][3][e]));
        mx = fmaxf(mx, __shfl_xor(mx, 1));
        mx = fmaxf(mx, __shfl_xor(mx, 2));
        mx = fmaxf(mx, __shfl_xor(mx, 4));
        mx = fmaxf(mx, __shfl_xor(mx, 8));
        float p0 = __expf(acc[i][0][e] - mx);
        float p1 = __expf(acc[i][1][e] - mx);
        float p2 = __expf(acc[i][2][e] - mx);
        float p3 = __expf(acc[i][3][e] - mx);
        float s = p0 + p1 + p2 + p3;
        s += __shfl_xor(s, 1);
        s += __shfl_xor(s, 2);
        s += __shfl_xor(s, 4);
        s += __shfl_xor(s, 8);
        float r = 1.f / (s * 8.0f);    // SCALE = sqrt(64) = 8
        acc[i][0][e] = p0 * r; acc[i][1][e] = p1 * r;
        acc[i][2][e] = p2 * r; acc[i][3][e] = p3 * r;
      }
  }
  #pragma unroll
  for (int i = 0; i < 4; i++)
    #pragma unroll
    for (int j = 0; j < 4; j++)
      #pragma unroll
      for (int e = 0; e < 4; e++){
        int row = m0 + wr + i * 16 + fq * 4 + e;
        int col = n0 + wc + j * 16 + fr;
        float v = acc[i][j][e];
        if constexpr (ADD_BIAS) v += bias[col];
        C[(size_t)row * ldc + col] = f2b(v);
      }
}

// ---- k row stats: per (b,c) row of k, max and 1/sum(exp(v-max)) -> stats
__global__ __launch_bounds__(256)
void kstats(const u16* __restrict__ kv, float* __restrict__ stats){
  int bx = blockIdx.x;                       // 0..4095
  int b = bx >> 9, c = bx & 511;
  const u16* kp = kv + (size_t)b * KV_B + (size_t)c * 4096;
  int tid = threadIdx.x;
  float v[16], mx = -1e30f;
  #pragma unroll
  for (int j = 0; j < 2; j++){
    short8 t = *(const short8*)(kp + j * 2048 + tid * 8);
    #pragma unroll
    for (int e = 0; e < 8; e++){ v[j * 8 + e] = b2f((u16)t[e]); mx = fmaxf(mx, v[j * 8 + e]); }
  }
  #pragma unroll
  for (int o = 32; o >= 1; o >>= 1) mx = fmaxf(mx, __shfl_xor(mx, o));
  __shared__ float redm[4], reds[4];
  if ((tid & 63) == 0) redm[tid >> 6] = mx;
  __syncthreads();
  mx = fmaxf(fmaxf(redm[0], redm[1]), fmaxf(redm[2], redm[3]));
  float s = 0.f;
  #pragma unroll
  for (int j = 0; j < 16; j++) s += __expf(v[j] - mx);
  #pragma unroll
  for (int o = 32; o >= 1; o >>= 1) s += __shfl_xor(s, o);
  if ((tid & 63) == 0) reds[tid >> 6] = s;
  __syncthreads();
  if (tid == 0){
    float st = reds[0] + reds[1] + reds[2] + reds[3];
    stats[bx] = mx;
    stats[4096 + bx] = 1.f / st;
  }
}

// ---- small 64x64-tile TN GEMM. MODE 0: ctx split-K partials (f32), with
//      k-softmax applied on the fly from stats. MODE 1: attnT = qT @ ctxT^T.
template<int MODE>
__global__ __launch_bounds__(256)
void gemm_small(const u16* __restrict__ kv, const u16* __restrict__ qT,
                const u16* __restrict__ ctxT, float* __restrict__ P,
                u16* __restrict__ attnT, const float* __restrict__ stats)
{
  constexpr int K = (MODE == 0) ? 1024 : 64;
  const int z = blockIdx.z;
  const u16* A; const u16* BT; int lda, ldb, m0 = 0;
  float mxr = 0.f, rsr = 1.f;
  const int tid = threadIdx.x;
  const int ar = tid >> 2, ac = (tid & 3) * 8;
  if constexpr (MODE == 0){
    int bh = z >> 2, s = z & 3, b = bh >> 3, h = bh & 7;
    A  = kv + (size_t)b * KV_B + (size_t)(h * 64) * 4096 + s * 1024;
    BT = kv + (size_t)b * KV_B + (size_t)(512 + h * 64) * 4096 + s * 1024;
    lda = 4096; ldb = 4096;
    int sidx = b * 512 + h * 64 + ar;
    mxr = stats[sidx]; rsr = stats[4096 + sidx];
  } else {
    int b = z >> 3, h = z & 7;
    A  = qT + (size_t)b * 4096 * 512 + h * 64;
    BT = ctxT + (size_t)z * 4096;
    lda = 512; ldb = 64;
    m0 = blockIdx.y * 64;
  }
  __shared__ u16 As[64 * 40];
  __shared__ u16 Bs[64 * 40];
  const int wid = tid >> 6, lane = tid & 63;
  const int wr = (wid >> 1) * 32, wc = (wid & 1) * 32;
  const int lr = lane & 15, kb = lane >> 4;
  f32x4 acc[2][2] = {};
  for (int k0 = 0; k0 < K; k0 += 32){
    short8 av = *(const short8*)(A + (size_t)(m0 + ar) * lda + k0 + ac);
    if constexpr (MODE == 0){
      short8 ao;
      #pragma unroll
      for (int e = 0; e < 8; e++)
        ao[e] = (short)f2b(__expf(b2f((u16)av[e]) - mxr) * rsr);
      av = ao;
    }
    *(short8*)(As + ar * 40 + ac) = av;
    *(short8*)(Bs + ar * 40 + ac) = *(const short8*)(BT + (size_t)ar * ldb + k0 + ac);
    __syncthreads();
    short8 a0 = *(const short8*)(As + (wr +      lr) * 40 + kb * 8);
    short8 a1 = *(const short8*)(As + (wr + 16 + lr) * 40 + kb * 8);
    short8 b0 = *(const short8*)(Bs + (wc +      lr) * 40 + kb * 8);
    short8 b1 = *(const short8*)(Bs + (wc + 16 + lr) * 40 + kb * 8);
    acc[0][0] = __builtin_amdgcn_mfma_f32_16x16x32_bf16(a0, b0, acc[0][0], 0, 0, 0);
    acc[0][1] = __builtin_amdgcn_mfma_f32_16x16x32_bf16(a0, b1, acc[0][1], 0, 0, 0);
    acc[1][0] = __builtin_amdgcn_mfma_f32_16x16x32_bf16(a1, b0, acc[1][0], 0, 0, 0);
    acc[1][1] = __builtin_amdgcn_mfma_f32_16x16x32_bf16(a1, b1, acc[1][1], 0, 0, 0);
    __syncthreads();
  }
  #pragma unroll
  for (int mi = 0; mi < 2; mi++)
    #pragma unroll
    for (int ni = 0; ni < 2; ni++)
      #pragma unroll
      for (int j = 0; j < 4; j++){
        int row = m0 + wr + mi * 16 + kb * 4 + j;
        int col = wc + ni * 16 + lr;
        if constexpr (MODE == 0){
          P[(size_t)z * 4096 + (size_t)row * 64 + col] = acc[mi][ni][j];
        } else {
          attnT[(size_t)(z >> 3) * 4096 * 512 + (size_t)row * 512 + (z & 7) * 64 + col]
            = f2b(acc[mi][ni][j]);
        }
      }
}

// ---- reduce 4 ctx split partials [d][e] f32 -> ctxT [e][d] bf16
__global__ __launch_bounds__(256)
void kreduce(const float* __restrict__ P, u16* __restrict__ ctxT){
  int o = blockIdx.x * 256 + threadIdx.x;    // 64*4096
  int bh = o >> 12, r = o & 4095, e = r >> 6, d = r & 63;
  const float* p = P + ((size_t)bh << 14) + (d << 6) + e;
  float s = p[0] + p[4096] + p[8192] + p[12288];
  ctxT[((size_t)bh << 12) + r] = f2b(s);
}

// ---- per-row (pixel) sumsq of out2T [n][512] -> inv
__global__ __launch_bounds__(256)
void ksumsq2(const u16* __restrict__ o2, float* __restrict__ inv){
  int t = threadIdx.x;
  int row = blockIdx.x * 32 + (t >> 3);
  const u16* p = o2 + (size_t)row * 512 + (size_t)(t & 7) * 64;
  float s = 0.f;
  #pragma unroll
  for (int j = 0; j < 8; j++){
    short8 v = *(const short8*)(p + j * 8);
    #pragma unroll
    for (int e = 0; e < 8; e++){ float f = b2f((u16)v[e]); s += f * f; }
  }
  s += __shfl_xor(s, 1); s += __shfl_xor(s, 2); s += __shfl_xor(s, 4);
  if ((t & 7) == 0) inv[row] = rsqrtf(s + 1e-12f);
}

// ---- rms2 + transpose: out2T [n][c] bf16 -> d_out [c][p] f32 (64x64 tiles)
__global__ __launch_bounds__(256)
void rms2T(const u16* __restrict__ o2, const float* __restrict__ g,
           const float* __restrict__ inv, float* __restrict__ out){
  __shared__ float lt[64][68];
  int t = threadIdx.x;
  int pg0 = blockIdx.x * 64, c0 = blockIdx.y * 64;
  int b = pg0 >> 12, p0 = pg0 & 4095;
  int cl = t & 63, w = t >> 6;
  float gf = g[c0 + cl] * SQRT512;
  #pragma unroll
  for (int j = 0; j < 16; j++){
    int p = j * 4 + w;
    float v = b2f(o2[(size_t)(pg0 + p) * 512 + c0 + cl]) * inv[pg0 + p] * gf;
    lt[cl][p] = v;
  }
  __syncthreads();
  int cr = t >> 2, pch = (t & 3) * 16;
  float* dst = out + ((size_t)(b * 512 + c0 + cr)) * 4096 + p0 + pch;
  const float* src = &lt[cr][pch];
  *(f32x4*)(dst +  0) = *(const f32x4*)(src +  0);
  *(f32x4*)(dst +  4) = *(const f32x4*)(src +  4);
  *(f32x4*)(dst +  8) = *(const f32x4*)(src +  8);
  *(f32x4*)(dst + 12) = *(const f32x4*)(src + 12);
}

extern "C" void kernel_launch(void* const* d_in, const int* in_sizes, int n_in,
                              void* d_out, int out_size, void* d_ws, size_t ws_size,
                              hipStream_t stream)
{
  (void)in_sizes; (void)n_in; (void)out_size; (void)ws_size;
  const float* x    = (const float*)d_in[0];
  const float* g1   = (const float*)d_in[1];
  const float* wqkv = (const float*)d_in[2];
  const float* wout = (const float*)d_in[3];
  const float* bout = (const float*)d_in[4];
  const float* g2   = (const float*)d_in[5];
  float* out = (float*)d_out;
  char* ws = (char*)d_ws;

  u16*   xnT   = (u16*)(ws);                          // S1
  float* P     = (float*)(ws);                        // S1 (after xnT dead)
  u16*   attnT = (u16*)(ws);                          // S1 (after P dead)
  u16*   qT    = (u16*)(ws + (size_t)33554432);       // S2
  u16*   out2T = (u16*)(ws + (size_t)33554432);       // S2 (after qT dead)
  u16*   kv    = (u16*)(ws + (size_t)67108864);       // S3
  u16*   wbf   = (u16*)(ws + (size_t)134217728);      // E: wq+wkv bf16 (1.5MB)
  u16*   ctxT  = (u16*)(ws + (size_t)134217728);      // E+0 (after wbf dead)
  float* stats = (float*)(ws + (size_t)134742016);    // E+524288 (after wbf dead)
  u16*   wkvbf = wbf + (size_t)512 * 512;
  u16*   woutbf= (u16*)(ws + (size_t)135790592);
  float* inv   = (float*)(ws + (size_t)136314880);    // F

  // 0) weights -> bf16
  kcvt<<<1024, 256, 0, stream>>>(wqkv, wout, wbf, woutbf);
  // 1) rms1: sumsq + normalize-transpose -> xnT [n][c]
  ksumsq<<<512, 256, 0, stream>>>(x, inv);
  knormT<<<dim3(512, 8), 256, 0, stream>>>(x, g1, inv, xnT);
  // 2) qT = softmax_d(xnT @ Wq^T)/8   (M=32768,N=512,K=512)
  gemm_big<0, 1><<<dim3(4, 256, 1), 256, 0, stream>>>(xnT, 0, 512, wbf, 0, 512,
                                                      qT, 0, 512, nullptr);
  //    kv_b = Wkv @ xn_b (per batch M=1024,N=4096,K=512), C row-major [c][n]
  gemm_big<0, 0><<<dim3(32, 8, 8), 256, 0, stream>>>(wkvbf, 0, 512,
                                                     xnT, (long)4096 * 512, 512,
                                                     kv, (long)KV_B, 4096, nullptr);
  // 3) k-softmax row stats (no rewrite of kv)
  kstats<<<4096, 256, 0, stream>>>(kv, stats);
  // 4) ctx split-K partials (softmax applied on the fly) + reduce -> ctxT
  gemm_small<0><<<dim3(1, 1, 256), 256, 0, stream>>>(kv, qT, ctxT, P, attnT, stats);
  kreduce<<<1024, 256, 0, stream>>>(P, ctxT);
  // 5) attnT = qT @ ctxT^T per (b,h)  (M=4096,N=64,K=64)
  gemm_small<1><<<dim3(1, 64, 64), 256, 0, stream>>>(kv, qT, ctxT, P, attnT, stats);
  // 6) out2T = attnT @ Wout^T + bias  (M=32768,N=512,K=512)
  gemm_big<1, 0><<<dim3(4, 256, 1), 256, 0, stream>>>(attnT, 0, 512, woutbf, 0, 512,
                                                      out2T, 0, 512, bout);
  // 7) rms2: row sumsq + normalize-transpose -> d_out [c][p] f32
  ksumsq2<<<1024, 256, 0, stream>>>(out2T, inv);
  rms2T<<<dim3(512, 8), 256, 0, stream>>>(out2T, g2, inv, out);
}

// Round 6
// 241.816 us; speedup vs baseline: 2.0246x; 1.0275x over previous
//
#include <hip/hip_runtime.h>

// LinearAttention on MI355X — round 6:
//  gemm_big: BK=32 double-buffer (32KB LDS -> 5 blocks/CU), counted vmcnt(4),
//  XOR swizzle (slot ^ (row>>1)&3) conflict-free at 64B row stride.
//  Fused rms1 (sumsq+normalize+transpose, one pass over x) with g1 folded into
//  Wqkv; fused rms2 (sumsq+normalize+transpose).
// Layouts: xnT[n][c], qT[n][512], kv[b][1024][n], ctxT[bh][e][d], attnT[n][512],
//          out2T[n][512].
// ws: S1=0(33.5M: xnT->P->attnT) S2=33.5M(qT->out2T) S3=67.1M(kv)
//     E=134217728: wbf(1.5M; later ctxT+stats) wout_bf@135790592

typedef unsigned short u16;
typedef __attribute__((ext_vector_type(8))) short short8;
typedef __attribute__((ext_vector_type(4))) short short4_t;
typedef __attribute__((ext_vector_type(4))) float f32x4;

static constexpr size_t XN_B = (size_t)512 * 4096;
static constexpr size_t KV_B = (size_t)1024 * 4096;
static constexpr float SQRT512 = 22.62741699796952f;

typedef const __attribute__((address_space(1))) unsigned int gu32;
typedef __attribute__((address_space(3))) unsigned int lu32;

__device__ __forceinline__ float b2f(u16 u){
  union { unsigned u; float f; } x; x.u = ((unsigned)u) << 16; return x.f;
}
__device__ __forceinline__ u16 f2b(float f){
  union { float f; unsigned u; } x; x.f = f;
  unsigned r = x.u + 0x7FFFu + ((x.u >> 16) & 1u);   // RNE
  return (u16)(r >> 16);
}
__device__ __forceinline__ void gl16(const u16* g, u16* l){
  __builtin_amdgcn_global_load_lds((gu32*)g, (lu32*)l, 16, 0, 0);
}

// ---- weights -> bf16; wqkv columns pre-scaled by g1[c]*sqrt(512)
__global__ __launch_bounds__(256)
void kcvt(const float* __restrict__ wqkv, const float* __restrict__ wout,
          const float* __restrict__ g1, u16* __restrict__ dq, u16* __restrict__ dw){
  size_t i = ((size_t)blockIdx.x * 256 + threadIdx.x) * 4;
  short4_t o;
  if (i < (size_t)786432){
    f32x4 v = *(const f32x4*)(wqkv + i);
    int c = (int)(i & 511);
    #pragma unroll
    for (int j = 0; j < 4; j++) o[j] = (short)f2b(v[j] * g1[c + j] * SQRT512);
    *(short4_t*)(dq + i) = o;
  } else {
    size_t off = i - 786432;
    f32x4 v = *(const f32x4*)(wout + off);
    #pragma unroll
    for (int j = 0; j < 4; j++) o[j] = (short)f2b(v[j]);
    *(short4_t*)(dw + off) = o;
  }
}

// ---- fused rms1: x [b][c][p] f32 -> xnT [p][c] bf16 = x * rsqrt(sumsq_c + eps)
// one block = 64 pixels; x read ONCE; g1 already folded into Wqkv.
__global__ __launch_bounds__(256)
void krms1(const float* __restrict__ x, u16* __restrict__ xnT){
  __shared__ u16 lt[64][514];     // [px][c], stride 514 -> conflict-free
  __shared__ float red[256];
  __shared__ float invs[64];
  int t = threadIdx.x;
  int pg0 = blockIdx.x * 64;
  int b = pg0 >> 12, p0 = pg0 & 4095;
  int px = t & 63, chunk = t >> 6;
  const float* xp = x + (size_t)b * XN_B + p0 + px;
  float s = 0.f;
  #pragma unroll 4
  for (int c = chunk * 128; c < chunk * 128 + 128; ++c){
    float v = xp[(size_t)c * 4096];
    lt[px][c] = f2b(v);
    s += v * v;
  }
  red[t] = s;
  __syncthreads();
  if (chunk == 0)
    invs[px] = rsqrtf(red[px] + red[px + 64] + red[px + 128] + red[px + 192] + 1e-12f);
  __syncthreads();
  int px2 = t >> 3, c0 = (t & 7) * 8;
  #pragma unroll
  for (int pass = 0; pass < 2; pass++){
    int pp = px2 + pass * 32;
    float iv = invs[pp];
    u16* dst = xnT + (size_t)(pg0 + pp) * 512;
    #pragma unroll
    for (int j = 0; j < 8; j++){
      int c = c0 + j * 64;
      short8 o;
      #pragma unroll
      for (int e = 0; e < 8; e++) o[e] = (short)f2b(b2f(lt[pp][c + e]) * iv);
      *(short8*)(dst + c) = o;
    }
  }
}

// ---- big TN GEMM: C[M][N] = A[M][K=512] @ BT[N][K]^T, 128^2 tile, BK=32 dbuf,
// counted vmcnt(4), slot^(row>>1)&3 swizzle (2-way conflicts = free).
// SMAX: per-row softmax over the wave's 64-col quadrant (= one head), then /8.
template<int ADD_BIAS, int SMAX>
__global__ __launch_bounds__(256)
void gemm_big(const u16* __restrict__ Ab, long astr, int lda,
              const u16* __restrict__ Bb, long bstr, int ldb,
              u16* __restrict__ Cb, long cstr, int ldc,
              const float* __restrict__ bias)
{
  constexpr int NT = 16;                // K=512 / BK=32
  const u16* A  = Ab + (size_t)blockIdx.z * astr;
  const u16* BT = Bb + (size_t)blockIdx.z * bstr;
  u16* C = Cb + (size_t)blockIdx.z * cstr;
  const int m0 = blockIdx.y * 128, n0 = blockIdx.x * 128;
  __shared__ u16 As[2][128 * 32];
  __shared__ u16 Bs[2][128 * 32];
  const int tid = threadIdx.x;
  const int lane = tid & 63, wid = tid >> 6;
  const int wr = (wid >> 1) * 64, wc = (wid & 1) * 64;
  const int fr = lane & 15, fq = lane >> 4;
  const int srow = tid >> 2;            // 64 rows per gl16 call
  const int sslot = tid & 3;            // 16B chunk slot in 64B row
  f32x4 acc[4][4] = {};

  auto STAGE = [&](int s, int t){
    const int k0 = t * 32;
    #pragma unroll
    for (int r = 0; r < 2; r++){
      int row = r * 64 + srow;
      int gj = (sslot ^ ((row >> 1) & 3)) * 8;
      gl16(A  + (size_t)(m0 + row) * lda + k0 + gj, &As[s][0] + r * 2048 + tid * 8);
      gl16(BT + (size_t)(n0 + row) * ldb + k0 + gj, &Bs[s][0] + r * 2048 + tid * 8);
    }
  };

  STAGE(0, 0);
  int cur = 0;
  for (int t = 0; t < NT; t++){
    if (t + 1 < NT){
      STAGE(cur ^ 1, t + 1);
      asm volatile("s_waitcnt vmcnt(4)" ::: "memory");   // tile t's 4 loads done
    } else {
      asm volatile("s_waitcnt vmcnt(0)" ::: "memory");
    }
    __builtin_amdgcn_s_barrier();
    __builtin_amdgcn_sched_barrier(0);
    short8 a[4], b[4];
    #pragma unroll
    for (int i = 0; i < 4; i++){
      int ra = wr + i * 16 + fr;
      a[i] = *(const short8*)(&As[cur][0] + ra * 32 + ((fq ^ ((ra >> 1) & 3)) * 8));
      int rb = wc + i * 16 + fr;
      b[i] = *(const short8*)(&Bs[cur][0] + rb * 32 + ((fq ^ ((rb >> 1) & 3)) * 8));
    }
    #pragma unroll
    for (int i = 0; i < 4; i++)
      #pragma unroll
      for (int j = 0; j < 4; j++)
        acc[i][j] = __builtin_amdgcn_mfma_f32_16x16x32_bf16(a[i], b[j], acc[i][j], 0, 0, 0);
    __builtin_amdgcn_sched_barrier(0);
    __builtin_amdgcn_s_barrier();
    cur ^= 1;
  }

  if constexpr (SMAX){
    #pragma unroll
    for (int i = 0; i < 4; i++)
      #pragma unroll
      for (int e = 0; e < 4; e++){
        float mx = fmaxf(fmaxf(acc[i][0][e], acc[i][1][e]),
                         fmaxf(acc[i][2][e], acc[i][3][e]));
        mx = fmaxf(mx, __shfl_xor(mx, 1));
        mx = fmaxf(mx, __shfl_xor(mx, 2));
        mx = fmaxf(mx, __shfl_xor(mx, 4));
        mx = fmaxf(mx, __shfl_xor(mx, 8));
        float p0 = __expf(acc[i][0][e] - mx);
        float p1 = __expf(acc[i][1][e] - mx);
        float p2 = __expf(acc[i][2][e] - mx);
        float p3 = __expf(acc[i][3][e] - mx);
        float s = p0 + p1 + p2 + p3;
        s += __shfl_xor(s, 1);
        s += __shfl_xor(s, 2);
        s += __shfl_xor(s, 4);
        s += __shfl_xor(s, 8);
        float r = 1.f / (s * 8.0f);    // SCALE = sqrt(64) = 8
        acc[i][0][e] = p0 * r; acc[i][1][e] = p1 * r;
        acc[i][2][e] = p2 * r; acc[i][3][e] = p3 * r;
      }
  }
  #pragma unroll
  for (int i = 0; i < 4; i++)
    #pragma unroll
    for (int j = 0; j < 4; j++)
      #pragma unroll
      for (int e = 0; e < 4; e++){
        int row = m0 + wr + i * 16 + fq * 4 + e;
        int col = n0 + wc + j * 16 + fr;
        float v = acc[i][j][e];
        if constexpr (ADD_BIAS) v += bias[col];
        C[(size_t)row * ldc + col] = f2b(v);
      }
}

// ---- k row stats: per (b,c) row of k, max and 1/sum(exp(v-max)) -> stats
__global__ __launch_bounds__(256)
void kstats(const u16* __restrict__ kv, float* __restrict__ stats){
  int bx = blockIdx.x;                       // 0..4095
  int b = bx >> 9, c = bx & 511;
  const u16* kp = kv + (size_t)b * KV_B + (size_t)c * 4096;
  int tid = threadIdx.x;
  float v[16], mx = -1e30f;
  #pragma unroll
  for (int j = 0; j < 2; j++){
    short8 t = *(const short8*)(kp + j * 2048 + tid * 8);
    #pragma unroll
    for (int e = 0; e < 8; e++){ v[j * 8 + e] = b2f((u16)t[e]); mx = fmaxf(mx, v[j * 8 + e]); }
  }
  #pragma unroll
  for (int o = 32; o >= 1; o >>= 1) mx = fmaxf(mx, __shfl_xor(mx, o));
  __shared__ float redm[4], reds[4];
  if ((tid & 63) == 0) redm[tid >> 6] = mx;
  __syncthreads();
  mx = fmaxf(fmaxf(redm[0], redm[1]), fmaxf(redm[2], redm[3]));
  float s = 0.f;
  #pragma unroll
  for (int j = 0; j < 16; j++) s += __expf(v[j] - mx);
  #pragma unroll
  for (int o = 32; o >= 1; o >>= 1) s += __shfl_xor(s, o);
  if ((tid & 63) == 0) reds[tid >> 6] = s;
  __syncthreads();
  if (tid == 0){
    float st = reds[0] + reds[1] + reds[2] + reds[3];
    stats[bx] = mx;
    stats[4096 + bx] = 1.f / st;
  }
}

// ---- small 64x64-tile TN GEMM. MODE 0: ctx split-K partials (f32), with
//      k-softmax applied on the fly from stats. MODE 1: attnT = qT @ ctxT^T.
template<int MODE>
__global__ __launch_bounds__(256)
void gemm_small(const u16* __restrict__ kv, const u16* __restrict__ qT,
                const u16* __restrict__ ctxT, float* __restrict__ P,
                u16* __restrict__ attnT, const float* __restrict__ stats)
{
  constexpr int K = (MODE == 0) ? 1024 : 64;
  const int z = blockIdx.z;
  const u16* A; const u16* BT; int lda, ldb, m0 = 0;
  float mxr = 0.f, rsr = 1.f;
  const int tid = threadIdx.x;
  const int ar = tid >> 2, ac = (tid & 3) * 8;
  if constexpr (MODE == 0){
    int bh = z >> 2, s = z & 3, b = bh >> 3, h = bh & 7;
    A  = kv + (size_t)b * KV_B + (size_t)(h * 64) * 4096 + s * 1024;
    BT = kv + (size_t)b * KV_B + (size_t)(512 + h * 64) * 4096 + s * 1024;
    lda = 4096; ldb = 4096;
    int sidx = b * 512 + h * 64 + ar;
    mxr = stats[sidx]; rsr = stats[4096 + sidx];
  } else {
    int b = z >> 3, h = z & 7;
    A  = qT + (size_t)b * 4096 * 512 + h * 64;
    BT = ctxT + (size_t)z * 4096;
    lda = 512; ldb = 64;
    m0 = blockIdx.y * 64;
  }
  __shared__ u16 As[64 * 40];
  __shared__ u16 Bs[64 * 40];
  const int wid = tid >> 6, lane = tid & 63;
  const int wr = (wid >> 1) * 32, wc = (wid & 1) * 32;
  const int lr = lane & 15, kb = lane >> 4;
  f32x4 acc[2][2] = {};
  for (int k0 = 0; k0 < K; k0 += 32){
    short8 av = *(const short8*)(A + (size_t)(m0 + ar) * lda + k0 + ac);
    if constexpr (MODE == 0){
      short8 ao;
      #pragma unroll
      for (int e = 0; e < 8; e++)
        ao[e] = (short)f2b(__expf(b2f((u16)av[e]) - mxr) * rsr);
      av = ao;
    }
    *(short8*)(As + ar * 40 + ac) = av;
    *(short8*)(Bs + ar * 40 + ac) = *(const short8*)(BT + (size_t)ar * ldb + k0 + ac);
    __syncthreads();
    short8 a0 = *(const short8*)(As + (wr +      lr) * 40 + kb * 8);
    short8 a1 = *(const short8*)(As + (wr + 16 + lr) * 40 + kb * 8);
    short8 b0 = *(const short8*)(Bs + (wc +      lr) * 40 + kb * 8);
    short8 b1 = *(const short8*)(Bs + (wc + 16 + lr) * 40 + kb * 8);
    acc[0][0] = __builtin_amdgcn_mfma_f32_16x16x32_bf16(a0, b0, acc[0][0], 0, 0, 0);
    acc[0][1] = __builtin_amdgcn_mfma_f32_16x16x32_bf16(a0, b1, acc[0][1], 0, 0, 0);
    acc[1][0] = __builtin_amdgcn_mfma_f32_16x16x32_bf16(a1, b0, acc[1][0], 0, 0, 0);
    acc[1][1] = __builtin_amdgcn_mfma_f32_16x16x32_bf16(a1, b1, acc[1][1], 0, 0, 0);
    __syncthreads();
  }
  #pragma unroll
  for (int mi = 0; mi < 2; mi++)
    #pragma unroll
    for (int ni = 0; ni < 2; ni++)
      #pragma unroll
      for (int j = 0; j < 4; j++){
        int row = m0 + wr + mi * 16 + kb * 4 + j;
        int col = wc + ni * 16 + lr;
        if constexpr (MODE == 0){
          P[(size_t)z * 4096 + (size_t)row * 64 + col] = acc[mi][ni][j];
        } else {
          attnT[(size_t)(z >> 3) * 4096 * 512 + (size_t)row * 512 + (z & 7) * 64 + col]
            = f2b(acc[mi][ni][j]);
        }
      }
}

// ---- reduce 4 ctx split partials [d][e] f32 -> ctxT [e][d] bf16
__global__ __launch_bounds__(256)
void kreduce(const float* __restrict__ P, u16* __restrict__ ctxT){
  int o = blockIdx.x * 256 + threadIdx.x;    // 64*4096
  int bh = o >> 12, r = o & 4095, e = r >> 6, d = r & 63;
  const float* p = P + ((size_t)bh << 14) + (d << 6) + e;
  float s = p[0] + p[4096] + p[8192] + p[12288];
  ctxT[((size_t)bh << 12) + r] = f2b(s);
}

// ---- fused rms2: out2T [n][c] bf16 -> d_out [c][p] f32, one pass
__global__ __launch_bounds__(256)
void krms2(const u16* __restrict__ o2, const float* __restrict__ g,
           float* __restrict__ out){
  __shared__ u16 lt[512][66];     // [c][px]
  __shared__ float invs[64];
  __shared__ float gl[512];
  int t = threadIdx.x;
  int pg0 = blockIdx.x * 64;
  int b = pg0 >> 12, p0 = pg0 & 4095;
  gl[t] = g[t] * SQRT512;
  gl[t + 256] = g[t + 256] * SQRT512;
  int px = t >> 3, c0 = (t & 7) * 8;
  float ss[2];
  #pragma unroll
  for (int pass = 0; pass < 2; pass++){
    int pp = px + pass * 32;
    const u16* src = o2 + (size_t)(pg0 + pp) * 512;
    float sacc = 0.f;
    #pragma unroll
    for (int j = 0; j < 8; j++){
      int c = c0 + j * 64;
      short8 v = *(const short8*)(src + c);
      #pragma unroll
      for (int e = 0; e < 8; e++){
        float f = b2f((u16)v[e]);
        sacc += f * f;
        lt[c + e][pp] = (u16)v[e];
      }
    }
    ss[pass] = sacc;
  }
  #pragma unroll
  for (int pass = 0; pass < 2; pass++){
    float s = ss[pass];
    s += __shfl_xor(s, 1); s += __shfl_xor(s, 2); s += __shfl_xor(s, 4);
    if ((t & 7) == 0) invs[px + pass * 32] = rsqrtf(s + 1e-12f);
  }
  __syncthreads();
  int c2 = t >> 2, pxc = (t & 3) * 16;
  #pragma unroll
  for (int pass = 0; pass < 8; pass++){
    int c = c2 + pass * 64;
    float gf = gl[c];
    float* dst = out + ((size_t)(b * 512 + c)) * 4096 + p0 + pxc;
    #pragma unroll
    for (int q = 0; q < 4; q++){
      f32x4 o;
      #pragma unroll
      for (int e = 0; e < 4; e++){
        int pp = pxc + q * 4 + e;
        o[e] = b2f(lt[c][pp]) * invs[pp] * gf;
      }
      *(f32x4*)(dst + q * 4) = o;
    }
  }
}

extern "C" void kernel_launch(void* const* d_in, const int* in_sizes, int n_in,
                              void* d_out, int out_size, void* d_ws, size_t ws_size,
                              hipStream_t stream)
{
  (void)in_sizes; (void)n_in; (void)out_size; (void)ws_size;
  const float* x    = (const float*)d_in[0];
  const float* g1   = (const float*)d_in[1];
  const float* wqkv = (const float*)d_in[2];
  const float* wout = (const float*)d_in[3];
  const float* bout = (const float*)d_in[4];
  const float* g2   = (const float*)d_in[5];
  float* out = (float*)d_out;
  char* ws = (char*)d_ws;

  u16*   xnT   = (u16*)(ws);                          // S1
  float* P     = (float*)(ws);                        // S1 (after xnT dead)
  u16*   attnT = (u16*)(ws);                          // S1 (after P dead)
  u16*   qT    = (u16*)(ws + (size_t)33554432);       // S2
  u16*   out2T = (u16*)(ws + (size_t)33554432);       // S2 (after qT dead)
  u16*   kv    = (u16*)(ws + (size_t)67108864);       // S3
  u16*   wbf   = (u16*)(ws + (size_t)134217728);      // E: wq+wkv bf16 (1.5MB)
  u16*   ctxT  = (u16*)(ws + (size_t)134217728);      // E+0 (after wbf dead)
  float* stats = (float*)(ws + (size_t)134742016);    // E+524288 (after wbf dead)
  u16*   wkvbf = wbf + (size_t)512 * 512;
  u16*   woutbf= (u16*)(ws + (size_t)135790592);

  // 0) weights -> bf16 (g1*sqrt512 folded into wqkv columns)
  kcvt<<<1024, 256, 0, stream>>>(wqkv, wout, g1, wbf, woutbf);
  // 1) fused rms1 -> xnT [n][c]  (x read once)
  krms1<<<512, 256, 0, stream>>>(x, xnT);
  // 2) qT = softmax_d(xnT @ Wq^T)/8   (M=32768,N=512,K=512)
  gemm_big<0, 1><<<dim3(4, 256, 1), 256, 0, stream>>>(xnT, 0, 512, wbf, 0, 512,
                                                      qT, 0, 512, nullptr);
  //    kv_b = Wkv @ xn_b (per batch M=1024,N=4096,K=512), C row-major [c][n]
  gemm_big<0, 0><<<dim3(32, 8, 8), 256, 0, stream>>>(wkvbf, 0, 512,
                                                     xnT, (long)4096 * 512, 512,
                                                     kv, (long)KV_B, 4096, nullptr);
  // 3) k-softmax row stats (no rewrite of kv)
  kstats<<<4096, 256, 0, stream>>>(kv, stats);
  // 4) ctx split-K partials (softmax applied on the fly) + reduce -> ctxT
  gemm_small<0><<<dim3(1, 1, 256), 256, 0, stream>>>(kv, qT, ctxT, P, attnT, stats);
  kreduce<<<1024, 256, 0, stream>>>(P, ctxT);
  // 5) attnT = qT @ ctxT^T per (b,h)  (M=4096,N=64,K=64)
  gemm_small<1><<<dim3(1, 64, 64), 256, 0, stream>>>(kv, qT, ctxT, P, attnT, stats);
  // 6) out2T = attnT @ Wout^T + bias  (M=32768,N=512,K=512)
  gemm_big<1, 0><<<dim3(4, 256, 1), 256, 0, stream>>>(attnT, 0, 512, woutbf, 0, 512,
                                                      out2T, 0, 512, bout);
  // 7) fused rms2 -> d_out [c][p] f32
  krms2<<<512, 256, 0, stream>>>(out2T, g2, out);
}

// Round 7
// 214.617 us; speedup vs baseline: 2.2811x; 1.1267x over previous
//
#include <hip/hip_runtime.h>

// LinearAttention on MI355X — round 7:
//  gemm_big: 128^2 tile, BK=32, 3-deep LDS ring + counted vmcnt(8) (never
//  drains to 0 mid-loop), XOR swizzle, s_setprio around MFMA cluster.
//  krms1/krms2: 32-pixel tiles (33KB LDS -> 4 blocks/CU).
// Layouts: xnT[n][c], qT[n][512], kv[b][1024][n], ctxT[bh][e][d], attnT[n][512],
//          out2T[n][512].
// ws: S1=0(33.5M: xnT->P->attnT) S2=33.5M(qT->out2T) S3=67.1M(kv)
//     E=134217728: wbf(1.5M; later ctxT+stats) wout_bf@135790592

typedef unsigned short u16;
typedef __attribute__((ext_vector_type(8))) short short8;
typedef __attribute__((ext_vector_type(4))) short short4_t;
typedef __attribute__((ext_vector_type(4))) float f32x4;

static constexpr size_t XN_B = (size_t)512 * 4096;
static constexpr size_t KV_B = (size_t)1024 * 4096;
static constexpr float SQRT512 = 22.62741699796952f;

typedef const __attribute__((address_space(1))) unsigned int gu32;
typedef __attribute__((address_space(3))) unsigned int lu32;

__device__ __forceinline__ float b2f(u16 u){
  union { unsigned u; float f; } x; x.u = ((unsigned)u) << 16; return x.f;
}
__device__ __forceinline__ u16 f2b(float f){
  union { float f; unsigned u; } x; x.f = f;
  unsigned r = x.u + 0x7FFFu + ((x.u >> 16) & 1u);   // RNE
  return (u16)(r >> 16);
}
__device__ __forceinline__ void gl16(const u16* g, u16* l){
  __builtin_amdgcn_global_load_lds((gu32*)g, (lu32*)l, 16, 0, 0);
}

// ---- weights -> bf16; wqkv columns pre-scaled by g1[c]*sqrt(512)
__global__ __launch_bounds__(256)
void kcvt(const float* __restrict__ wqkv, const float* __restrict__ wout,
          const float* __restrict__ g1, u16* __restrict__ dq, u16* __restrict__ dw){
  size_t i = ((size_t)blockIdx.x * 256 + threadIdx.x) * 4;
  short4_t o;
  if (i < (size_t)786432){
    f32x4 v = *(const f32x4*)(wqkv + i);
    int c = (int)(i & 511);
    #pragma unroll
    for (int j = 0; j < 4; j++) o[j] = (short)f2b(v[j] * g1[c + j] * SQRT512);
    *(short4_t*)(dq + i) = o;
  } else {
    size_t off = i - 786432;
    f32x4 v = *(const f32x4*)(wout + off);
    #pragma unroll
    for (int j = 0; j < 4; j++) o[j] = (short)f2b(v[j]);
    *(short4_t*)(dw + off) = o;
  }
}

// ---- fused rms1: x [b][c][p] f32 -> xnT [p][c] bf16, 32 px/block (33KB LDS)
__global__ __launch_bounds__(256)
void krms1(const float* __restrict__ x, u16* __restrict__ xnT){
  __shared__ u16 lt[32][514];
  __shared__ float red[256];
  __shared__ float invs[32];
  int t = threadIdx.x;
  int pg0 = blockIdx.x * 32;
  int b = pg0 >> 12, p0 = pg0 & 4095;
  int px = t & 31, chunk = t >> 5;          // 8 chunks x 64 channels
  const float* xp = x + (size_t)b * XN_B + p0 + px;
  float s = 0.f;
  #pragma unroll 4
  for (int c = chunk * 64; c < chunk * 64 + 64; ++c){
    float v = xp[(size_t)c * 4096];
    lt[px][c] = f2b(v);
    s += v * v;
  }
  red[t] = s;
  __syncthreads();
  if (chunk == 0){
    float tt = red[px] + red[px + 32] + red[px + 64] + red[px + 96]
             + red[px + 128] + red[px + 160] + red[px + 192] + red[px + 224];
    invs[px] = rsqrtf(tt + 1e-12f);
  }
  __syncthreads();
  int px2 = t >> 3, c0 = (t & 7) * 8;
  float iv = invs[px2];
  u16* dst = xnT + (size_t)(pg0 + px2) * 512;
  #pragma unroll
  for (int j = 0; j < 8; j++){
    int c = c0 + j * 64;
    short8 o;
    #pragma unroll
    for (int e = 0; e < 8; e++) o[e] = (short)f2b(b2f(lt[px2][c + e]) * iv);
    *(short8*)(dst + c) = o;
  }
}

// ---- big TN GEMM: C[M][N] = A[M][K=512] @ BT[N][K]^T, 128^2 tile, BK=32,
// 3-deep LDS ring, counted vmcnt(8), XOR swizzle, setprio around MFMA.
// SMAX: per-row softmax over the wave's 64-col quadrant (= one head), then /8.
template<int ADD_BIAS, int SMAX>
__global__ __launch_bounds__(256)
void gemm_big(const u16* __restrict__ Ab, long astr, int lda,
              const u16* __restrict__ Bb, long bstr, int ldb,
              u16* __restrict__ Cb, long cstr, int ldc,
              const float* __restrict__ bias)
{
  constexpr int NT = 16;                // K=512 / BK=32
  const u16* A  = Ab + (size_t)blockIdx.z * astr;
  const u16* BT = Bb + (size_t)blockIdx.z * bstr;
  u16* C = Cb + (size_t)blockIdx.z * cstr;
  const int m0 = blockIdx.y * 128, n0 = blockIdx.x * 128;
  __shared__ u16 As[3][128 * 32];       // 3-ring: 48KB total (A+B)
  __shared__ u16 Bs[3][128 * 32];
  const int tid = threadIdx.x;
  const int lane = tid & 63, wid = tid >> 6;
  const int wr = (wid >> 1) * 64, wc = (wid & 1) * 64;
  const int fr = lane & 15, fq = lane >> 4;
  const int srow = tid >> 2;            // 64 rows per gl16 call
  const int sslot = tid & 3;            // 16B chunk slot in 64B row
  f32x4 acc[4][4] = {};

  auto STAGE = [&](int s, int t){
    const int k0 = t * 32;
    #pragma unroll
    for (int r = 0; r < 2; r++){
      int row = r * 64 + srow;
      int gj = (sslot ^ ((row >> 1) & 3)) * 8;
      gl16(A  + (size_t)(m0 + row) * lda + k0 + gj, &As[s][0] + r * 2048 + tid * 8);
      gl16(BT + (size_t)(n0 + row) * ldb + k0 + gj, &Bs[s][0] + r * 2048 + tid * 8);
    }
  };

  STAGE(0, 0);
  STAGE(1, 1);
  for (int t = 0; t < NT; t++){
    const int cur = t % 3;
    if (t + 2 < NT){
      STAGE((t + 2) % 3, t + 2);
      asm volatile("s_waitcnt vmcnt(8)" ::: "memory");   // tile t's loads done
    } else if (t + 1 < NT){
      asm volatile("s_waitcnt vmcnt(4)" ::: "memory");
    } else {
      asm volatile("s_waitcnt vmcnt(0)" ::: "memory");
    }
    __builtin_amdgcn_s_barrier();
    __builtin_amdgcn_sched_barrier(0);
    short8 a[4], b[4];
    #pragma unroll
    for (int i = 0; i < 4; i++){
      int ra = wr + i * 16 + fr;
      a[i] = *(const short8*)(&As[cur][0] + ra * 32 + ((fq ^ ((ra >> 1) & 3)) * 8));
      int rb = wc + i * 16 + fr;
      b[i] = *(const short8*)(&Bs[cur][0] + rb * 32 + ((fq ^ ((rb >> 1) & 3)) * 8));
    }
    __builtin_amdgcn_s_setprio(1);
    #pragma unroll
    for (int i = 0; i < 4; i++)
      #pragma unroll
      for (int j = 0; j < 4; j++)
        acc[i][j] = __builtin_amdgcn_mfma_f32_16x16x32_bf16(a[i], b[j], acc[i][j], 0, 0, 0);
    __builtin_amdgcn_s_setprio(0);
    __builtin_amdgcn_sched_barrier(0);
    __builtin_amdgcn_s_barrier();       // buf[cur] free for re-stage at t+1
  }

  if constexpr (SMAX){
    #pragma unroll
    for (int i = 0; i < 4; i++)
      #pragma unroll
      for (int e = 0; e < 4; e++){
        float mx = fmaxf(fmaxf(acc[i][0][e], acc[i][1][e]),
                         fmaxf(acc[i][2][e], acc[i][3][e]));
        mx = fmaxf(mx, __shfl_xor(mx, 1));
        mx = fmaxf(mx, __shfl_xor(mx, 2));
        mx = fmaxf(mx, __shfl_xor(mx, 4));
        mx = fmaxf(mx, __shfl_xor(mx, 8));
        float p0 = __expf(acc[i][0][e] - mx);
        float p1 = __expf(acc[i][1][e] - mx);
        float p2 = __expf(acc[i][2][e] - mx);
        float p3 = __expf(acc[i][3][e] - mx);
        float s = p0 + p1 + p2 + p3;
        s += __shfl_xor(s, 1);
        s += __shfl_xor(s, 2);
        s += __shfl_xor(s, 4);
        s += __shfl_xor(s, 8);
        float r = 1.f / (s * 8.0f);    // SCALE = sqrt(64) = 8
        acc[i][0][e] = p0 * r; acc[i][1][e] = p1 * r;
        acc[i][2][e] = p2 * r; acc[i][3][e] = p3 * r;
      }
  }
  #pragma unroll
  for (int i = 0; i < 4; i++)
    #pragma unroll
    for (int j = 0; j < 4; j++)
      #pragma unroll
      for (int e = 0; e < 4; e++){
        int row = m0 + wr + i * 16 + fq * 4 + e;
        int col = n0 + wc + j * 16 + fr;
        float v = acc[i][j][e];
        if constexpr (ADD_BIAS) v += bias[col];
        C[(size_t)row * ldc + col] = f2b(v);
      }
}

// ---- k row stats: per (b,c) row of k, max and 1/sum(exp(v-max)) -> stats
__global__ __launch_bounds__(256)
void kstats(const u16* __restrict__ kv, float* __restrict__ stats){
  int bx = blockIdx.x;                       // 0..4095
  int b = bx >> 9, c = bx & 511;
  const u16* kp = kv + (size_t)b * KV_B + (size_t)c * 4096;
  int tid = threadIdx.x;
  float v[16], mx = -1e30f;
  #pragma unroll
  for (int j = 0; j < 2; j++){
    short8 t = *(const short8*)(kp + j * 2048 + tid * 8);
    #pragma unroll
    for (int e = 0; e < 8; e++){ v[j * 8 + e] = b2f((u16)t[e]); mx = fmaxf(mx, v[j * 8 + e]); }
  }
  #pragma unroll
  for (int o = 32; o >= 1; o >>= 1) mx = fmaxf(mx, __shfl_xor(mx, o));
  __shared__ float redm[4], reds[4];
  if ((tid & 63) == 0) redm[tid >> 6] = mx;
  __syncthreads();
  mx = fmaxf(fmaxf(redm[0], redm[1]), fmaxf(redm[2], redm[3]));
  float s = 0.f;
  #pragma unroll
  for (int j = 0; j < 16; j++) s += __expf(v[j] - mx);
  #pragma unroll
  for (int o = 32; o >= 1; o >>= 1) s += __shfl_xor(s, o);
  if ((tid & 63) == 0) reds[tid >> 6] = s;
  __syncthreads();
  if (tid == 0){
    float st = reds[0] + reds[1] + reds[2] + reds[3];
    stats[bx] = mx;
    stats[4096 + bx] = 1.f / st;
  }
}

// ---- small 64x64-tile TN GEMM. MODE 0: ctx split-K partials (f32), with
//      k-softmax applied on the fly from stats. MODE 1: attnT = qT @ ctxT^T.
template<int MODE>
__global__ __launch_bounds__(256)
void gemm_small(const u16* __restrict__ kv, const u16* __restrict__ qT,
                const u16* __restrict__ ctxT, float* __restrict__ P,
                u16* __restrict__ attnT, const float* __restrict__ stats)
{
  constexpr int K = (MODE == 0) ? 1024 : 64;
  const int z = blockIdx.z;
  const u16* A; const u16* BT; int lda, ldb, m0 = 0;
  float mxr = 0.f, rsr = 1.f;
  const int tid = threadIdx.x;
  const int ar = tid >> 2, ac = (tid & 3) * 8;
  if constexpr (MODE == 0){
    int bh = z >> 2, s = z & 3, b = bh >> 3, h = bh & 7;
    A  = kv + (size_t)b * KV_B + (size_t)(h * 64) * 4096 + s * 1024;
    BT = kv + (size_t)b * KV_B + (size_t)(512 + h * 64) * 4096 + s * 1024;
    lda = 4096; ldb = 4096;
    int sidx = b * 512 + h * 64 + ar;
    mxr = stats[sidx]; rsr = stats[4096 + sidx];
  } else {
    int b = z >> 3, h = z & 7;
    A  = qT + (size_t)b * 4096 * 512 + h * 64;
    BT = ctxT + (size_t)z * 4096;
    lda = 512; ldb = 64;
    m0 = blockIdx.y * 64;
  }
  __shared__ u16 As[64 * 40];
  __shared__ u16 Bs[64 * 40];
  const int wid = tid >> 6, lane = tid & 63;
  const int wr = (wid >> 1) * 32, wc = (wid & 1) * 32;
  const int lr = lane & 15, kb = lane >> 4;
  f32x4 acc[2][2] = {};
  for (int k0 = 0; k0 < K; k0 += 32){
    short8 av = *(const short8*)(A + (size_t)(m0 + ar) * lda + k0 + ac);
    if constexpr (MODE == 0){
      short8 ao;
      #pragma unroll
      for (int e = 0; e < 8; e++)
        ao[e] = (short)f2b(__expf(b2f((u16)av[e]) - mxr) * rsr);
      av = ao;
    }
    *(short8*)(As + ar * 40 + ac) = av;
    *(short8*)(Bs + ar * 40 + ac) = *(const short8*)(BT + (size_t)ar * ldb + k0 + ac);
    __syncthreads();
    short8 a0 = *(const short8*)(As + (wr +      lr) * 40 + kb * 8);
    short8 a1 = *(const short8*)(As + (wr + 16 + lr) * 40 + kb * 8);
    short8 b0 = *(const short8*)(Bs + (wc +      lr) * 40 + kb * 8);
    short8 b1 = *(const short8*)(Bs + (wc + 16 + lr) * 40 + kb * 8);
    acc[0][0] = __builtin_amdgcn_mfma_f32_16x16x32_bf16(a0, b0, acc[0][0], 0, 0, 0);
    acc[0][1] = __builtin_amdgcn_mfma_f32_16x16x32_bf16(a0, b1, acc[0][1], 0, 0, 0);
    acc[1][0] = __builtin_amdgcn_mfma_f32_16x16x32_bf16(a1, b0, acc[1][0], 0, 0, 0);
    acc[1][1] = __builtin_amdgcn_mfma_f32_16x16x32_bf16(a1, b1, acc[1][1], 0, 0, 0);
    __syncthreads();
  }
  #pragma unroll
  for (int mi = 0; mi < 2; mi++)
    #pragma unroll
    for (int ni = 0; ni < 2; ni++)
      #pragma unroll
      for (int j = 0; j < 4; j++){
        int row = m0 + wr + mi * 16 + kb * 4 + j;
        int col = wc + ni * 16 + lr;
        if constexpr (MODE == 0){
          P[(size_t)z * 4096 + (size_t)row * 64 + col] = acc[mi][ni][j];
        } else {
          attnT[(size_t)(z >> 3) * 4096 * 512 + (size_t)row * 512 + (z & 7) * 64 + col]
            = f2b(acc[mi][ni][j]);
        }
      }
}

// ---- reduce 4 ctx split partials [d][e] f32 -> ctxT [e][d] bf16
__global__ __launch_bounds__(256)
void kreduce(const float* __restrict__ P, u16* __restrict__ ctxT){
  int o = blockIdx.x * 256 + threadIdx.x;    // 64*4096
  int bh = o >> 12, r = o & 4095, e = r >> 6, d = r & 63;
  const float* p = P + ((size_t)bh << 14) + (d << 6) + e;
  float s = p[0] + p[4096] + p[8192] + p[12288];
  ctxT[((size_t)bh << 12) + r] = f2b(s);
}

// ---- fused rms2: out2T [n][c] bf16 -> d_out [c][p] f32, 32 px/block
__global__ __launch_bounds__(256)
void krms2(const u16* __restrict__ o2, const float* __restrict__ g,
           float* __restrict__ out){
  __shared__ u16 lt[32][514];
  __shared__ float invs[32];
  __shared__ float gl[512];
  int t = threadIdx.x;
  int pg0 = blockIdx.x * 32;
  int b = pg0 >> 12, p0 = pg0 & 4095;
  gl[t] = g[t] * SQRT512;
  gl[t + 256] = g[t + 256] * SQRT512;
  int px2 = t >> 3, c0 = (t & 7) * 8;
  const u16* src = o2 + (size_t)(pg0 + px2) * 512;
  float s = 0.f;
  #pragma unroll
  for (int j = 0; j < 8; j++){
    int c = c0 + j * 64;
    short8 v = *(const short8*)(src + c);
    *(short8*)&lt[px2][c] = v;
    #pragma unroll
    for (int e = 0; e < 8; e++){ float f = b2f((u16)v[e]); s += f * f; }
  }
  s += __shfl_xor(s, 1); s += __shfl_xor(s, 2); s += __shfl_xor(s, 4);
  if ((t & 7) == 0) invs[px2] = rsqrtf(s + 1e-12f);
  __syncthreads();
  int c2 = t >> 2, pxc = (t & 3) * 8;
  float ivv[8];
  #pragma unroll
  for (int e = 0; e < 8; e++) ivv[e] = invs[pxc + e];
  #pragma unroll
  for (int pass = 0; pass < 8; pass++){
    int c = c2 + pass * 64;
    float gf = gl[c];
    float* dst = out + ((size_t)(b * 512 + c)) * 4096 + p0 + pxc;
    #pragma unroll
    for (int q = 0; q < 2; q++){
      f32x4 o;
      #pragma unroll
      for (int e = 0; e < 4; e++){
        int pp = q * 4 + e;
        o[e] = b2f(lt[pxc + pp][c]) * ivv[pp] * gf;
      }
      *(f32x4*)(dst + q * 4) = o;
    }
  }
}

extern "C" void kernel_launch(void* const* d_in, const int* in_sizes, int n_in,
                              void* d_out, int out_size, void* d_ws, size_t ws_size,
                              hipStream_t stream)
{
  (void)in_sizes; (void)n_in; (void)out_size; (void)ws_size;
  const float* x    = (const float*)d_in[0];
  const float* g1   = (const float*)d_in[1];
  const float* wqkv = (const float*)d_in[2];
  const float* wout = (const float*)d_in[3];
  const float* bout = (const float*)d_in[4];
  const float* g2   = (const float*)d_in[5];
  float* out = (float*)d_out;
  char* ws = (char*)d_ws;

  u16*   xnT   = (u16*)(ws);                          // S1
  float* P     = (float*)(ws);                        // S1 (after xnT dead)
  u16*   attnT = (u16*)(ws);                          // S1 (after P dead)
  u16*   qT    = (u16*)(ws + (size_t)33554432);       // S2
  u16*   out2T = (u16*)(ws + (size_t)33554432);       // S2 (after qT dead)
  u16*   kv    = (u16*)(ws + (size_t)67108864);       // S3
  u16*   wbf   = (u16*)(ws + (size_t)134217728);      // E: wq+wkv bf16 (1.5MB)
  u16*   ctxT  = (u16*)(ws + (size_t)134217728);      // E+0 (after wbf dead)
  float* stats = (float*)(ws + (size_t)134742016);    // E+524288 (after wbf dead)
  u16*   wkvbf = wbf + (size_t)512 * 512;
  u16*   woutbf= (u16*)(ws + (size_t)135790592);

  // 0) weights -> bf16 (g1*sqrt512 folded into wqkv columns)
  kcvt<<<1024, 256, 0, stream>>>(wqkv, wout, g1, wbf, woutbf);
  // 1) fused rms1 -> xnT [n][c]  (x read once)
  krms1<<<1024, 256, 0, stream>>>(x, xnT);
  // 2) qT = softmax_d(xnT @ Wq^T)/8   (M=32768,N=512,K=512)
  gemm_big<0, 1><<<dim3(4, 256, 1), 256, 0, stream>>>(xnT, 0, 512, wbf, 0, 512,
                                                      qT, 0, 512, nullptr);
  //    kv_b = Wkv @ xn_b (per batch M=1024,N=4096,K=512), C row-major [c][n]
  gemm_big<0, 0><<<dim3(32, 8, 8), 256, 0, stream>>>(wkvbf, 0, 512,
                                                     xnT, (long)4096 * 512, 512,
                                                     kv, (long)KV_B, 4096, nullptr);
  // 3) k-softmax row stats (no rewrite of kv)
  kstats<<<4096, 256, 0, stream>>>(kv, stats);
  // 4) ctx split-K partials (softmax applied on the fly) + reduce -> ctxT
  gemm_small<0><<<dim3(1, 1, 256), 256, 0, stream>>>(kv, qT, ctxT, P, attnT, stats);
  kreduce<<<1024, 256, 0, stream>>>(P, ctxT);
  // 5) attnT = qT @ ctxT^T per (b,h)  (M=4096,N=64,K=64)
  gemm_small<1><<<dim3(1, 64, 64), 256, 0, stream>>>(kv, qT, ctxT, P, attnT, stats);
  // 6) out2T = attnT @ Wout^T + bias  (M=32768,N=512,K=512)
  gemm_big<1, 0><<<dim3(4, 256, 1), 256, 0, stream>>>(attnT, 0, 512, woutbf, 0, 512,
                                                      out2T, 0, 512, bout);
  // 7) fused rms2 -> d_out [c][p] f32
  krms2<<<1024, 256, 0, stream>>>(out2T, g2, out);
}

// Round 8
// 198.126 us; speedup vs baseline: 2.4710x; 1.0832x over previous
//
#include <hip/hip_runtime.h>

// LinearAttention on MI355X — round 8:
//  gemm_big: 256x256 tile, 8 waves (512 thr), BK=32 double-buffer, counted
//  vmcnt(4), XOR swizzle, setprio. 32 MFMA/wave/phase.
//  W_out folded through ctx: M_b = Wout_h @ ctx_bh  (kills attn GEMM + attnT).
// Layouts: xnT[n][c], qT[n][512], kv[b][1024][n], ctxD[bh][d][e], M[b][co][hd],
//          out2T[n][512] (in S3 after kv dead).
// ws: S1=0: xnT -> P(4MB) -> M@+8M(4MB) | S2=33.5M: qT | S3=67.1M: kv -> out2T
//     E=134217728: wbf(1.5M) -> ctxD(512K)+stats | woutbf@135790592

typedef unsigned short u16;
typedef __attribute__((ext_vector_type(8))) short short8;
typedef __attribute__((ext_vector_type(4))) short short4_t;
typedef __attribute__((ext_vector_type(4))) float f32x4;

static constexpr size_t XN_B = (size_t)512 * 4096;
static constexpr size_t KV_B = (size_t)1024 * 4096;
static constexpr float SQRT512 = 22.62741699796952f;

typedef const __attribute__((address_space(1))) unsigned int gu32;
typedef __attribute__((address_space(3))) unsigned int lu32;

__device__ __forceinline__ float b2f(u16 u){
  union { unsigned u; float f; } x; x.u = ((unsigned)u) << 16; return x.f;
}
__device__ __forceinline__ u16 f2b(float f){
  union { float f; unsigned u; } x; x.f = f;
  unsigned r = x.u + 0x7FFFu + ((x.u >> 16) & 1u);   // RNE
  return (u16)(r >> 16);
}
__device__ __forceinline__ void gl16(const u16* g, u16* l){
  __builtin_amdgcn_global_load_lds((gu32*)g, (lu32*)l, 16, 0, 0);
}

// ---- weights -> bf16; wqkv columns pre-scaled by g1[c]*sqrt(512)
__global__ __launch_bounds__(256)
void kcvt(const float* __restrict__ wqkv, const float* __restrict__ wout,
          const float* __restrict__ g1, u16* __restrict__ dq, u16* __restrict__ dw){
  size_t i = ((size_t)blockIdx.x * 256 + threadIdx.x) * 4;
  short4_t o;
  if (i < (size_t)786432){
    f32x4 v = *(const f32x4*)(wqkv + i);
    int c = (int)(i & 511);
    #pragma unroll
    for (int j = 0; j < 4; j++) o[j] = (short)f2b(v[j] * g1[c + j] * SQRT512);
    *(short4_t*)(dq + i) = o;
  } else {
    size_t off = i - 786432;
    f32x4 v = *(const f32x4*)(wout + off);
    #pragma unroll
    for (int j = 0; j < 4; j++) o[j] = (short)f2b(v[j]);
    *(short4_t*)(dw + off) = o;
  }
}

// ---- fused rms1: x [b][c][p] f32 -> xnT [p][c] bf16, 32 px/block
__global__ __launch_bounds__(256)
void krms1(const float* __restrict__ x, u16* __restrict__ xnT){
  __shared__ u16 lt[32][514];
  __shared__ float red[256];
  __shared__ float invs[32];
  int t = threadIdx.x;
  int pg0 = blockIdx.x * 32;
  int b = pg0 >> 12, p0 = pg0 & 4095;
  int px = t & 31, chunk = t >> 5;
  const float* xp = x + (size_t)b * XN_B + p0 + px;
  float s = 0.f;
  #pragma unroll 4
  for (int c = chunk * 64; c < chunk * 64 + 64; ++c){
    float v = xp[(size_t)c * 4096];
    lt[px][c] = f2b(v);
    s += v * v;
  }
  red[t] = s;
  __syncthreads();
  if (chunk == 0){
    float tt = red[px] + red[px + 32] + red[px + 64] + red[px + 96]
             + red[px + 128] + red[px + 160] + red[px + 192] + red[px + 224];
    invs[px] = rsqrtf(tt + 1e-12f);
  }
  __syncthreads();
  int px2 = t >> 3, c0 = (t & 7) * 8;
  float iv = invs[px2];
  u16* dst = xnT + (size_t)(pg0 + px2) * 512;
  #pragma unroll
  for (int j = 0; j < 8; j++){
    int c = c0 + j * 64;
    short8 o;
    #pragma unroll
    for (int e = 0; e < 8; e++) o[e] = (short)f2b(b2f(lt[px2][c + e]) * iv);
    *(short8*)(dst + c) = o;
  }
}

// ---- big TN GEMM: C[M][N] = A[M][K=512] @ BT[N][K]^T, 256^2 tile, 8 waves,
// BK=32 dbuf, counted vmcnt(4), XOR swizzle, setprio. 32 MFMA/wave/phase.
// SMAX: per-row softmax over the wave's 64-col quadrant (= one head), then /8.
template<int ADD_BIAS, int SMAX>
__global__ __launch_bounds__(512)
void gemm_big(const u16* __restrict__ Ab, long astr, int lda,
              const u16* __restrict__ Bb, long bstr, int ldb,
              u16* __restrict__ Cb, long cstr, int ldc,
              const float* __restrict__ bias)
{
  constexpr int NT = 16;                // K=512 / BK=32
  const u16* A  = Ab + (size_t)blockIdx.z * astr;
  const u16* BT = Bb + (size_t)blockIdx.z * bstr;
  u16* C = Cb + (size_t)blockIdx.z * cstr;
  const int m0 = blockIdx.y * 256, n0 = blockIdx.x * 256;
  __shared__ u16 As[2][256 * 32];       // 32 KB
  __shared__ u16 Bs[2][256 * 32];       // 32 KB  (total 64 KB)
  const int tid = threadIdx.x;
  const int lane = tid & 63, wid = tid >> 6;
  const int wr = (wid >> 2) * 128, wc = (wid & 3) * 64;   // 2M x 4N waves
  const int fr = lane & 15, fq = lane >> 4;
  const int srow = tid >> 2;            // 128 rows per gl16 call
  const int sslot = tid & 3;            // 16B chunk slot in 64B row
  f32x4 acc[8][4] = {};

  auto STAGE = [&](int s, int t){
    const int k0 = t * 32;
    #pragma unroll
    for (int r = 0; r < 2; r++){
      int row = r * 128 + srow;
      int gj = (sslot ^ ((row >> 1) & 3)) * 8;
      gl16(A  + (size_t)(m0 + row) * lda + k0 + gj, &As[s][0] + r * 4096 + tid * 8);
      gl16(BT + (size_t)(n0 + row) * ldb + k0 + gj, &Bs[s][0] + r * 4096 + tid * 8);
    }
  };

  STAGE(0, 0);
  int cur = 0;
  for (int t = 0; t < NT; t++){
    if (t + 1 < NT){
      STAGE(cur ^ 1, t + 1);
      asm volatile("s_waitcnt vmcnt(4)" ::: "memory");   // tile t's 4 loads done
    } else {
      asm volatile("s_waitcnt vmcnt(0)" ::: "memory");
    }
    __builtin_amdgcn_s_barrier();
    __builtin_amdgcn_sched_barrier(0);
    short8 a[8], b[4];
    #pragma unroll
    for (int i = 0; i < 8; i++){
      int ra = wr + i * 16 + fr;
      a[i] = *(const short8*)(&As[cur][0] + ra * 32 + ((fq ^ ((ra >> 1) & 3)) * 8));
    }
    #pragma unroll
    for (int j = 0; j < 4; j++){
      int rb = wc + j * 16 + fr;
      b[j] = *(const short8*)(&Bs[cur][0] + rb * 32 + ((fq ^ ((rb >> 1) & 3)) * 8));
    }
    __builtin_amdgcn_s_setprio(1);
    #pragma unroll
    for (int i = 0; i < 8; i++)
      #pragma unroll
      for (int j = 0; j < 4; j++)
        acc[i][j] = __builtin_amdgcn_mfma_f32_16x16x32_bf16(a[i], b[j], acc[i][j], 0, 0, 0);
    __builtin_amdgcn_s_setprio(0);
    __builtin_amdgcn_sched_barrier(0);
    __builtin_amdgcn_s_barrier();
    cur ^= 1;
  }

  if constexpr (SMAX){
    #pragma unroll
    for (int i = 0; i < 8; i++)
      #pragma unroll
      for (int e = 0; e < 4; e++){
        float mx = fmaxf(fmaxf(acc[i][0][e], acc[i][1][e]),
                         fmaxf(acc[i][2][e], acc[i][3][e]));
        mx = fmaxf(mx, __shfl_xor(mx, 1));
        mx = fmaxf(mx, __shfl_xor(mx, 2));
        mx = fmaxf(mx, __shfl_xor(mx, 4));
        mx = fmaxf(mx, __shfl_xor(mx, 8));
        float p0 = __expf(acc[i][0][e] - mx);
        float p1 = __expf(acc[i][1][e] - mx);
        float p2 = __expf(acc[i][2][e] - mx);
        float p3 = __expf(acc[i][3][e] - mx);
        float s = p0 + p1 + p2 + p3;
        s += __shfl_xor(s, 1);
        s += __shfl_xor(s, 2);
        s += __shfl_xor(s, 4);
        s += __shfl_xor(s, 8);
        float r = 1.f / (s * 8.0f);    // SCALE = sqrt(64) = 8
        acc[i][0][e] = p0 * r; acc[i][1][e] = p1 * r;
        acc[i][2][e] = p2 * r; acc[i][3][e] = p3 * r;
      }
  }
  #pragma unroll
  for (int i = 0; i < 8; i++)
    #pragma unroll
    for (int j = 0; j < 4; j++)
      #pragma unroll
      for (int e = 0; e < 4; e++){
        int row = m0 + wr + i * 16 + fq * 4 + e;
        int col = n0 + wc + j * 16 + fr;
        float v = acc[i][j][e];
        if constexpr (ADD_BIAS) v += bias[col];
        C[(size_t)row * ldc + col] = f2b(v);
      }
}

// ---- k row stats: per (b,c) row of k, max and 1/sum(exp(v-max)) -> stats
__global__ __launch_bounds__(256)
void kstats(const u16* __restrict__ kv, float* __restrict__ stats){
  int bx = blockIdx.x;                       // 0..4095
  int b = bx >> 9, c = bx & 511;
  const u16* kp = kv + (size_t)b * KV_B + (size_t)c * 4096;
  int tid = threadIdx.x;
  float v[16], mx = -1e30f;
  #pragma unroll
  for (int j = 0; j < 2; j++){
    short8 t = *(const short8*)(kp + j * 2048 + tid * 8);
    #pragma unroll
    for (int e = 0; e < 8; e++){ v[j * 8 + e] = b2f((u16)t[e]); mx = fmaxf(mx, v[j * 8 + e]); }
  }
  #pragma unroll
  for (int o = 32; o >= 1; o >>= 1) mx = fmaxf(mx, __shfl_xor(mx, o));
  __shared__ float redm[4], reds[4];
  if ((tid & 63) == 0) redm[tid >> 6] = mx;
  __syncthreads();
  mx = fmaxf(fmaxf(redm[0], redm[1]), fmaxf(redm[2], redm[3]));
  float s = 0.f;
  #pragma unroll
  for (int j = 0; j < 16; j++) s += __expf(v[j] - mx);
  #pragma unroll
  for (int o = 32; o >= 1; o >>= 1) s += __shfl_xor(s, o);
  if ((tid & 63) == 0) reds[tid >> 6] = s;
  __syncthreads();
  if (tid == 0){
    float st = reds[0] + reds[1] + reds[2] + reds[3];
    stats[bx] = mx;
    stats[4096 + bx] = 1.f / st;
  }
}

// ---- ctx split-K partials: P[z=bh*4+s][d][e] f32, softmax applied on the fly
__global__ __launch_bounds__(256)
void gemm_ctx(const u16* __restrict__ kv, float* __restrict__ P,
              const float* __restrict__ stats)
{
  constexpr int K = 1024;
  const int z = blockIdx.z;
  const int tid = threadIdx.x;
  const int ar = tid >> 2, ac = (tid & 3) * 8;
  int bh = z >> 2, sp = z & 3, b = bh >> 3, h = bh & 7;
  const u16* A  = kv + (size_t)b * KV_B + (size_t)(h * 64) * 4096 + sp * 1024;
  const u16* BT = kv + (size_t)b * KV_B + (size_t)(512 + h * 64) * 4096 + sp * 1024;
  int sidx = b * 512 + h * 64 + ar;
  float mxr = stats[sidx], rsr = stats[4096 + sidx];
  __shared__ u16 As[64 * 40];
  __shared__ u16 Bs[64 * 40];
  const int wid = tid >> 6, lane = tid & 63;
  const int wr = (wid >> 1) * 32, wc = (wid & 1) * 32;
  const int lr = lane & 15, kb = lane >> 4;
  f32x4 acc[2][2] = {};
  for (int k0 = 0; k0 < K; k0 += 32){
    short8 av = *(const short8*)(A + (size_t)ar * 4096 + k0 + ac);
    short8 ao;
    #pragma unroll
    for (int e = 0; e < 8; e++)
      ao[e] = (short)f2b(__expf(b2f((u16)av[e]) - mxr) * rsr);
    *(short8*)(As + ar * 40 + ac) = ao;
    *(short8*)(Bs + ar * 40 + ac) = *(const short8*)(BT + (size_t)ar * 4096 + k0 + ac);
    __syncthreads();
    short8 a0 = *(const short8*)(As + (wr +      lr) * 40 + kb * 8);
    short8 a1 = *(const short8*)(As + (wr + 16 + lr) * 40 + kb * 8);
    short8 b0 = *(const short8*)(Bs + (wc +      lr) * 40 + kb * 8);
    short8 b1 = *(const short8*)(Bs + (wc + 16 + lr) * 40 + kb * 8);
    acc[0][0] = __builtin_amdgcn_mfma_f32_16x16x32_bf16(a0, b0, acc[0][0], 0, 0, 0);
    acc[0][1] = __builtin_amdgcn_mfma_f32_16x16x32_bf16(a0, b1, acc[0][1], 0, 0, 0);
    acc[1][0] = __builtin_amdgcn_mfma_f32_16x16x32_bf16(a1, b0, acc[1][0], 0, 0, 0);
    acc[1][1] = __builtin_amdgcn_mfma_f32_16x16x32_bf16(a1, b1, acc[1][1], 0, 0, 0);
    __syncthreads();
  }
  #pragma unroll
  for (int mi = 0; mi < 2; mi++)
    #pragma unroll
    for (int ni = 0; ni < 2; ni++)
      #pragma unroll
      for (int j = 0; j < 4; j++){
        int row = wr + mi * 16 + kb * 4 + j;
        int col = wc + ni * 16 + lr;
        P[(size_t)z * 4096 + (size_t)row * 64 + col] = acc[mi][ni][j];
      }
}

// ---- reduce 4 ctx split partials -> ctxD [bh][d*64+e] bf16 (elementwise)
__global__ __launch_bounds__(256)
void kreduce(const float* __restrict__ P, u16* __restrict__ ctxD){
  int o = blockIdx.x * 256 + threadIdx.x;    // 64*4096
  int bh = o >> 12, r = o & 4095;
  const float* p = P + ((size_t)bh << 14) + r;
  float s = p[0] + p[4096] + p[8192] + p[12288];
  ctxD[((size_t)bh << 12) + r] = f2b(s);
}

// ---- M_b[co][h*64+d] = sum_e Wout[co][h*64+e] * ctx_bh[d][e]  (64x64 tiles)
__global__ __launch_bounds__(256)
void gemm_ctxw(const u16* __restrict__ woutbf, const u16* __restrict__ ctxD,
               u16* __restrict__ M)
{
  const int z = blockIdx.z;                  // bh
  const int b = z >> 3, h = z & 7;
  const int m0 = blockIdx.y * 64;
  const u16* A  = woutbf + h * 64;           // [co][e] lda=512
  const u16* BT = ctxD + (size_t)z * 4096;   // [d][e] ldb=64
  const int tid = threadIdx.x;
  const int ar = tid >> 2, ac = (tid & 3) * 8;
  __shared__ u16 As[64 * 40];
  __shared__ u16 Bs[64 * 40];
  const int wid = tid >> 6, lane = tid & 63;
  const int wr = (wid >> 1) * 32, wc = (wid & 1) * 32;
  const int lr = lane & 15, kb = lane >> 4;
  f32x4 acc[2][2] = {};
  for (int k0 = 0; k0 < 64; k0 += 32){
    *(short8*)(As + ar * 40 + ac) = *(const short8*)(A + (size_t)(m0 + ar) * 512 + k0 + ac);
    *(short8*)(Bs + ar * 40 + ac) = *(const short8*)(BT + (size_t)ar * 64 + k0 + ac);
    __syncthreads();
    short8 a0 = *(const short8*)(As + (wr +      lr) * 40 + kb * 8);
    short8 a1 = *(const short8*)(As + (wr + 16 + lr) * 40 + kb * 8);
    short8 b0 = *(const short8*)(Bs + (wc +      lr) * 40 + kb * 8);
    short8 b1 = *(const short8*)(Bs + (wc + 16 + lr) * 40 + kb * 8);
    acc[0][0] = __builtin_amdgcn_mfma_f32_16x16x32_bf16(a0, b0, acc[0][0], 0, 0, 0);
    acc[0][1] = __builtin_amdgcn_mfma_f32_16x16x32_bf16(a0, b1, acc[0][1], 0, 0, 0);
    acc[1][0] = __builtin_amdgcn_mfma_f32_16x16x32_bf16(a1, b0, acc[1][0], 0, 0, 0);
    acc[1][1] = __builtin_amdgcn_mfma_f32_16x16x32_bf16(a1, b1, acc[1][1], 0, 0, 0);
    __syncthreads();
  }
  #pragma unroll
  for (int mi = 0; mi < 2; mi++)
    #pragma unroll
    for (int ni = 0; ni < 2; ni++)
      #pragma unroll
      for (int j = 0; j < 4; j++){
        int row = m0 + wr + mi * 16 + kb * 4 + j;
        int col = wc + ni * 16 + lr;
        M[(size_t)b * 262144 + (size_t)row * 512 + h * 64 + col] = f2b(acc[mi][ni][j]);
      }
}

// ---- fused rms2: out2T [n][c] bf16 -> d_out [c][p] f32, 32 px/block
__global__ __launch_bounds__(256)
void krms2(const u16* __restrict__ o2, const float* __restrict__ g,
           float* __restrict__ out){
  __shared__ u16 lt[32][514];
  __shared__ float invs[32];
  __shared__ float gl[512];
  int t = threadIdx.x;
  int pg0 = blockIdx.x * 32;
  int b = pg0 >> 12, p0 = pg0 & 4095;
  gl[t] = g[t] * SQRT512;
  gl[t + 256] = g[t + 256] * SQRT512;
  int px2 = t >> 3, c0 = (t & 7) * 8;
  const u16* src = o2 + (size_t)(pg0 + px2) * 512;
  float s = 0.f;
  #pragma unroll
  for (int j = 0; j < 8; j++){
    int c = c0 + j * 64;
    short8 v = *(const short8*)(src + c);
    *(short8*)&lt[px2][c] = v;
    #pragma unroll
    for (int e = 0; e < 8; e++){ float f = b2f((u16)v[e]); s += f * f; }
  }
  s += __shfl_xor(s, 1); s += __shfl_xor(s, 2); s += __shfl_xor(s, 4);
  if ((t & 7) == 0) invs[px2] = rsqrtf(s + 1e-12f);
  __syncthreads();
  int c2 = t >> 2, pxc = (t & 3) * 8;
  float ivv[8];
  #pragma unroll
  for (int e = 0; e < 8; e++) ivv[e] = invs[pxc + e];
  #pragma unroll
  for (int pass = 0; pass < 8; pass++){
    int c = c2 + pass * 64;
    float gf = gl[c];
    float* dst = out + ((size_t)(b * 512 + c)) * 4096 + p0 + pxc;
    #pragma unroll
    for (int q = 0; q < 2; q++){
      f32x4 o;
      #pragma unroll
      for (int e = 0; e < 4; e++){
        int pp = q * 4 + e;
        o[e] = b2f(lt[pxc + pp][c]) * ivv[pp] * gf;
      }
      *(f32x4*)(dst + q * 4) = o;
    }
  }
}

extern "C" void kernel_launch(void* const* d_in, const int* in_sizes, int n_in,
                              void* d_out, int out_size, void* d_ws, size_t ws_size,
                              hipStream_t stream)
{
  (void)in_sizes; (void)n_in; (void)out_size; (void)ws_size;
  const float* x    = (const float*)d_in[0];
  const float* g1   = (const float*)d_in[1];
  const float* wqkv = (const float*)d_in[2];
  const float* wout = (const float*)d_in[3];
  const float* bout = (const float*)d_in[4];
  const float* g2   = (const float*)d_in[5];
  float* out = (float*)d_out;
  char* ws = (char*)d_ws;

  u16*   xnT   = (u16*)(ws);                          // S1 (dead after kv GEMM)
  float* P     = (float*)(ws);                        // S1+0, 4MB (after xnT dead)
  u16*   M     = (u16*)(ws + (size_t)8388608);        // S1+8M, 4MB (after kreduce)
  u16*   qT    = (u16*)(ws + (size_t)33554432);       // S2 (alive until out2 done)
  u16*   kv    = (u16*)(ws + (size_t)67108864);       // S3 (dead after gemm_ctx)
  u16*   out2T = (u16*)(ws + (size_t)67108864);       // S3 (after kv dead)
  u16*   wbf   = (u16*)(ws + (size_t)134217728);      // E: wq+wkv bf16 (1.5MB)
  u16*   ctxD  = (u16*)(ws + (size_t)134217728);      // E+0 (after wbf dead)
  float* stats = (float*)(ws + (size_t)134742016);    // E+524288 (after wbf dead)
  u16*   wkvbf = wbf + (size_t)512 * 512;
  u16*   woutbf= (u16*)(ws + (size_t)135790592);

  // 0) weights -> bf16 (g1*sqrt512 folded into wqkv columns)
  kcvt<<<1024, 256, 0, stream>>>(wqkv, wout, g1, wbf, woutbf);
  // 1) fused rms1 -> xnT [n][c]  (x read once)
  krms1<<<1024, 256, 0, stream>>>(x, xnT);
  // 2) qT = softmax_d(xnT @ Wq^T)/8   (M=32768,N=512,K=512)
  gemm_big<0, 1><<<dim3(2, 128, 1), 512, 0, stream>>>(xnT, 0, 512, wbf, 0, 512,
                                                      qT, 0, 512, nullptr);
  //    kv_b = Wkv @ xn_b (per batch M=1024,N=4096,K=512), C row-major [c][n]
  gemm_big<0, 0><<<dim3(16, 4, 8), 512, 0, stream>>>(wkvbf, 0, 512,
                                                     xnT, (long)4096 * 512, 512,
                                                     kv, (long)KV_B, 4096, nullptr);
  // 3) k-softmax row stats (no rewrite of kv)
  kstats<<<4096, 256, 0, stream>>>(kv, stats);
  // 4) ctx split-K partials (softmax on the fly) + elementwise reduce -> ctxD
  gemm_ctx<<<dim3(1, 1, 256), 256, 0, stream>>>(kv, P, stats);
  kreduce<<<1024, 256, 0, stream>>>(P, ctxD);
  // 5) M_b = Wout_h @ ctx_bh (fold W_out through ctx; kills attn GEMM)
  gemm_ctxw<<<dim3(1, 8, 64), 256, 0, stream>>>(woutbf, ctxD, M);
  // 6) out2T = qT @ M_b^T + bias  (per batch M=4096,N=512,K=512)
  gemm_big<1, 0><<<dim3(2, 16, 8), 512, 0, stream>>>(qT, (long)4096 * 512, 512,
                                                     M, (long)262144, 512,
                                                     out2T, (long)4096 * 512, 512, bout);
  // 7) fused rms2 -> d_out [c][p] f32
  krms2<<<1024, 256, 0, stream>>>(out2T, g2, out);
}